// Round 6
// baseline (494.676 us; speedup 1.0000x reference)
//
#include <hip/hip_runtime.h>
#include <cfloat>

#define KC 512        // codes
#define DD 64         // dim
#define HW 4096       // 64*64
#define NPIX 131072   // 32*64*64
#define QSIZE 8388608 // 32*64*64*64
#define PXB 128       // pixels per tile
#define NTILE (NPIX / PXB)   // 1024 tiles
#define NBLK (NTILE / 2)     // 512 persistent blocks, 2 tiles each
#define NTH 512       // 8 waves
#define MARGIN 4.0e-3f  // covers 2*screen-err + 2*trunc-err (~2.1e-3) with slack

typedef short short8 __attribute__((ext_vector_type(8)));   // 8 bf16 MFMA operand
typedef float f32x4 __attribute__((ext_vector_type(4)));
typedef float nfloat4 __attribute__((ext_vector_type(4)));
typedef unsigned long long u64;

__device__ __forceinline__ unsigned short bf16_rne(float f) {
    unsigned int u = __float_as_uint(f);
    u += 0x7FFFu + ((u >> 16) & 1u);
    return (unsigned short)(u >> 16);
}

// LDS-only barrier: syncs waves + orders DS ops, but does NOT drain vmcnt —
// in-flight NT output stores keep streaming across it. Legal here: the kernel
// has no global RAW (all global writes are to write-only outputs).
__device__ __forceinline__ void barrier_lds_only() {
    asm volatile("s_waitcnt lgkmcnt(0)" ::: "memory");
    __builtin_amdgcn_s_barrier();
    __builtin_amdgcn_sched_barrier(0);
}

// --- prep (once per launch, validated R10): swizzled bf16 B-frag codebook
// (64 KB) + np-pairwise w2. Slot s=(ct*2+kc)*64+ln holds
// w[ct*16+(ln&15)][kc*32+(ln>>4)*8 .. +8) as bf16x8.
__global__ __launch_bounds__(1024) void prep(
    const float* __restrict__ w, float* __restrict__ w2g,
    uint4* __restrict__ wswz) {
  const int gt = blockIdx.x * 1024 + threadIdx.x;   // 0..4095
  {
    int ct = gt >> 7, kc = (gt >> 6) & 1, ln = gt & 63;
    int n = ln & 15, q = ln >> 4;
    const float* wp = w + (ct * 16 + n) * DD + kc * 32 + q * 8;
    nfloat4 f0 = *(const nfloat4*)(wp);
    nfloat4 f1 = *(const nfloat4*)(wp + 4);
    uint4 u;
    u.x = (unsigned)bf16_rne(f0[0]) | ((unsigned)bf16_rne(f0[1]) << 16);
    u.y = (unsigned)bf16_rne(f0[2]) | ((unsigned)bf16_rne(f0[3]) << 16);
    u.z = (unsigned)bf16_rne(f1[0]) | ((unsigned)bf16_rne(f1[1]) << 16);
    u.w = (unsigned)bf16_rne(f1[2]) | ((unsigned)bf16_rne(f1[3]) << 16);
    wswz[gt] = u;
  }
  if (gt < KC) {      // w2g[k]: numpy-pairwise fp32 sum of squares
    const float* wk = w + gt * DD;
    float r0 = __fmul_rn(wk[0], wk[0]), r1 = __fmul_rn(wk[1], wk[1]),
          r2 = __fmul_rn(wk[2], wk[2]), r3 = __fmul_rn(wk[3], wk[3]),
          r4 = __fmul_rn(wk[4], wk[4]), r5 = __fmul_rn(wk[5], wk[5]),
          r6 = __fmul_rn(wk[6], wk[6]), r7 = __fmul_rn(wk[7], wk[7]);
    #pragma unroll
    for (int i = 8; i < DD; i += 8) {
      r0 = __fadd_rn(r0, __fmul_rn(wk[i+0], wk[i+0]));
      r1 = __fadd_rn(r1, __fmul_rn(wk[i+1], wk[i+1]));
      r2 = __fadd_rn(r2, __fmul_rn(wk[i+2], wk[i+2]));
      r3 = __fadd_rn(r3, __fmul_rn(wk[i+3], wk[i+3]));
      r4 = __fadd_rn(r4, __fmul_rn(wk[i+4], wk[i+4]));
      r5 = __fadd_rn(r5, __fmul_rn(wk[i+5], wk[i+5]));
      r6 = __fadd_rn(r6, __fmul_rn(wk[i+6], wk[i+6]));
      r7 = __fadd_rn(r7, __fmul_rn(wk[i+7], wk[i+7]));
    }
    w2g[gt] = __fadd_rn(__fadd_rn(__fadd_rn(r0, r1), __fadd_rn(r2, r3)),
                        __fadd_rn(__fadd_rn(r4, r5), __fadd_rn(r6, r7)));
  }
}

// ======== per-tile phase helpers ====

__device__ __forceinline__ void tile_prelude(
    const float* __restrict__ xt, float* Xs, u64 (*candm)[8],
    short8& a0, short8& a1, int tid, int lane, int wv) {
  // zero candidate masks (2 u64 per thread)
  ((u64*)candm)[tid] = 0;
  ((u64*)candm)[tid + NTH] = 0;
  // Xs: np-pairwise ||x||^2 (one px per thread)
  if (tid < PXB) {
    const float* xp = xt + tid;
    float r0 = __fmul_rn(xp[0*HW], xp[0*HW]), r1 = __fmul_rn(xp[1*HW], xp[1*HW]),
          r2 = __fmul_rn(xp[2*HW], xp[2*HW]), r3 = __fmul_rn(xp[3*HW], xp[3*HW]),
          r4 = __fmul_rn(xp[4*HW], xp[4*HW]), r5 = __fmul_rn(xp[5*HW], xp[5*HW]),
          r6 = __fmul_rn(xp[6*HW], xp[6*HW]), r7 = __fmul_rn(xp[7*HW], xp[7*HW]);
    #pragma unroll
    for (int i = 8; i < DD; i += 8) {
      r0 = __fadd_rn(r0, __fmul_rn(xp[(size_t)(i+0)*HW], xp[(size_t)(i+0)*HW]));
      r1 = __fadd_rn(r1, __fmul_rn(xp[(size_t)(i+1)*HW], xp[(size_t)(i+1)*HW]));
      r2 = __fadd_rn(r2, __fmul_rn(xp[(size_t)(i+2)*HW], xp[(size_t)(i+2)*HW]));
      r3 = __fadd_rn(r3, __fmul_rn(xp[(size_t)(i+3)*HW], xp[(size_t)(i+3)*HW]));
      r4 = __fadd_rn(r4, __fmul_rn(xp[(size_t)(i+4)*HW], xp[(size_t)(i+4)*HW]));
      r5 = __fadd_rn(r5, __fmul_rn(xp[(size_t)(i+5)*HW], xp[(size_t)(i+5)*HW]));
      r6 = __fadd_rn(r6, __fmul_rn(xp[(size_t)(i+6)*HW], xp[(size_t)(i+6)*HW]));
      r7 = __fadd_rn(r7, __fmul_rn(xp[(size_t)(i+7)*HW], xp[(size_t)(i+7)*HW]));
    }
    Xs[tid] = __fadd_rn(__fadd_rn(__fadd_rn(r0, r1), __fadd_rn(r2, r3)),
                        __fadd_rn(__fadd_rn(r4, r5), __fadd_rn(r6, r7)));
  }
  // A-frags: A[m=lane&15][k=quad*8+j] of (-2x), bf16
  const int am = lane & 15, aq = lane >> 4;
  const float* xa = xt + wv * 16 + am;
  #pragma unroll
  for (int j = 0; j < 8; ++j) {
    a0[j] = (short)bf16_rne(-2.0f * xa[(size_t)(aq * 8 + j) * HW]);
    a1[j] = (short)bf16_rne(-2.0f * xa[(size_t)(32 + aq * 8 + j) * HW]);
  }
}

__device__ __forceinline__ void tile_refine(
    const float* __restrict__ xt, const float* __restrict__ w,
    const float* w2s, const float* Xs, const u64 (*candm)[8],
    int* sidx, float* __restrict__ out_idx, int bix, int tid, int lane) {
  const int px = tid >> 2, part = tid & 3;
  const float X = Xs[px];
  const float* xr = xt + px;
  float bestd = FLT_MAX; int bk = 1 << 30;
  for (int wd = part * 2; wd < part * 2 + 2; ++wd) {
    u64 msk = candm[px][wd];
    while (msk) {
      int bit = __ffsll((unsigned long long)msk) - 1;
      msk &= msk - 1;
      int k = wd * 64 + bit;
      const float* wp = w + k * DD;
      float P = 0.f;                       // ascending-d fma chain (BLAS order)
      #pragma unroll
      for (int dc = 0; dc < 16; ++dc) {
        nfloat4 w4 = *(const nfloat4*)(wp + dc * 4);
        P = __fmaf_rn(xr[(size_t)(dc * 4 + 0) * HW], w4[0], P);
        P = __fmaf_rn(xr[(size_t)(dc * 4 + 1) * HW], w4[1], P);
        P = __fmaf_rn(xr[(size_t)(dc * 4 + 2) * HW], w4[2], P);
        P = __fmaf_rn(xr[(size_t)(dc * 4 + 3) * HW], w4[3], P);
      }
      float dist = __fsub_rn(__fadd_rn(X, w2s[k]), __fadd_rn(P, P));
      if (dist < bestd || (dist == bestd && k < bk)) { bestd = dist; bk = k; }
    }
  }
  // merge the 4 parts (tie -> smaller k, matching np.argmin first-index)
  float od = __shfl_down(bestd, 1); int ok = __shfl_down(bk, 1);
  if ((lane & 3) < 3 && (od < bestd || (od == bestd && ok < bk))) { bestd = od; bk = ok; }
  od = __shfl_down(bestd, 2); ok = __shfl_down(bk, 2);
  if ((lane & 3) < 2 && (od < bestd || (od == bestd && ok < bk))) { bestd = od; bk = ok; }
  if (part == 0) {
    sidx[px] = bk;
    out_idx[bix * PXB + px] = (float)bk;
  }
}

__device__ __forceinline__ float tile_quant(
    const float* __restrict__ xt, const float* __restrict__ w,
    const int* sidx, float* __restrict__ qb, int tid) {
  float lsum = 0.f;
  for (int i = tid; i < PXB * DD; i += NTH) {   // 16 iters
    int d = i >> 7, pp = i & 127;
    float qv = w[sidx[pp] * DD + d];      // L1/L2-resident gather
    float dv = qv - xt[(size_t)d * HW + pp];
    lsum = __fmaf_rn(dv, dv, lsum);
    __builtin_nontemporal_store(qv, qb + (size_t)d * HW + pp);
  }
  return lsum;
}

__device__ __forceinline__ void tile_enc(
    const int* sidx, float* __restrict__ basep, int tid) {
  // one-hot enc (base ≡ 1 mod 4 floats: 3-head, aligned body, 1-tail)
  for (int t = tid; t < 16383; t += NTH) {
    int u = 3 + 4 * t;
    nfloat4 v;
    #pragma unroll
    for (int j = 0; j < 4; ++j) {
      int e = u + j;
      v[j] = (sidx[e >> 9] == (e & 511)) ? 1.0f : 0.0f;
    }
    __builtin_nontemporal_store(v, (nfloat4*)(basep + u));
  }
  if (tid < 3) basep[tid] = (sidx[0] == tid) ? 1.0f : 0.0f;
  else if (tid == 3) basep[PXB * KC - 1] = (sidx[127] == 511) ? 1.0f : 0.0f;
}

// ---- single-pass screen: one MFMA sweep; acc (= w2_k - 2x.w_k, |.|<~0.1)
// truncation-packed to bf16 pairs in 64 VGPRs (p[], constant-indexed via full
// unroll); min on raw f32; flag phase unpacks registers — no 2nd codebook
// sweep, no LDS codebook. Truncation rounds DOWN -> flag set is a conservative
// superset; refine recovers the exact np argmin. B-frags from L2-resident wswz.
#define SCREEN_AND_FLAG(a0_, a1_)                                              \
  {                                                                            \
    float m0 = FLT_MAX, m1 = FLT_MAX, m2 = FLT_MAX, m3 = FLT_MAX;              \
    _Pragma("unroll")                                                          \
    for (int ct = 0; ct < 32; ++ct) {                                          \
      float wk2 = w2s[ct * 16 + cn];                                           \
      short8 b0 = wsw8[ct * 128 + lane];                                       \
      short8 b1 = wsw8[ct * 128 + 64 + lane];                                  \
      f32x4 acc = {wk2, wk2, wk2, wk2};                                        \
      acc = __builtin_amdgcn_mfma_f32_16x16x32_bf16(a0_, b0, acc, 0, 0, 0);    \
      acc = __builtin_amdgcn_mfma_f32_16x16x32_bf16(a1_, b1, acc, 0, 0, 0);    \
      p[2 * ct] = (__float_as_uint(acc[1]) & 0xFFFF0000u) |                    \
                  (__float_as_uint(acc[0]) >> 16);                             \
      p[2 * ct + 1] = (__float_as_uint(acc[3]) & 0xFFFF0000u) |                \
                      (__float_as_uint(acc[2]) >> 16);                         \
      m0 = fminf(m0, acc[0]); m1 = fminf(m1, acc[1]);                          \
      m2 = fminf(m2, acc[2]); m3 = fminf(m3, acc[3]);                          \
    }                                                                          \
    _Pragma("unroll")                                                          \
    for (int s = 1; s < 16; s <<= 1) {                                         \
      m0 = fminf(m0, __shfl_xor(m0, s));                                       \
      m1 = fminf(m1, __shfl_xor(m1, s));                                       \
      m2 = fminf(m2, __shfl_xor(m2, s));                                       \
      m3 = fminf(m3, __shfl_xor(m3, s));                                       \
    }                                                                          \
    const float t0 = m0 + MARGIN, t1 = m1 + MARGIN,                            \
                t2 = m2 + MARGIN, t3 = m3 + MARGIN;                            \
    _Pragma("unroll")                                                          \
    for (int ct = 0; ct < 32; ++ct) {                                          \
      float f0 = __uint_as_float(p[2 * ct] << 16);                             \
      float f1 = __uint_as_float(p[2 * ct] & 0xFFFF0000u);                     \
      float f2 = __uint_as_float(p[2 * ct + 1] << 16);                         \
      float f3 = __uint_as_float(p[2 * ct + 1] & 0xFFFF0000u);                 \
      u64 bm0 = __ballot(f0 <= t0);                                            \
      u64 bm1 = __ballot(f1 <= t1);                                            \
      u64 bm2 = __ballot(f2 <= t2);                                            \
      u64 bm3 = __ballot(f3 <= t3);                                            \
      if (lane < 4) {                                                          \
        u64 mk = (lane == 0) ? bm0 : (lane == 1) ? bm1 : (lane == 2) ? bm2 : bm3; \
        int word = ct >> 2, sh = (ct & 3) * 16;                                \
        _Pragma("unroll")                                                      \
        for (int q = 0; q < 4; ++q) {                                          \
          u64 bits = (mk >> (q * 16)) & 0xFFFFull;                             \
          if (bits) candm[wv * 16 + q * 4 + lane][word] |= bits << sh;         \
        }                                                                      \
      }                                                                        \
    }                                                                          \
  }

// --- main R16: R4's persistent 2-tile structure + single-pass screen.
// LDS 75 KB -> 11 KB (codebook dropped; B-frags direct from L2). One codebook
// sweep per tile instead of two; one fewer barrier phase. Numerics of refine/
// quant/enc/loss bit-identical to R0/R4; screen is a conservative superset.
__global__ __launch_bounds__(NTH, 4) void vq_fused(
    const float* __restrict__ x, const float* __restrict__ w,
    const float* __restrict__ w2g, const short8* __restrict__ wsw8,
    float* __restrict__ out_q, float* __restrict__ out_enc,
    float* __restrict__ out_idx, double* __restrict__ partial) {

  __shared__ float w2s[KC];           // 2 KB: np-exact ||w_k||^2
  __shared__ u64 candm[PXB][8];       // 8 KB: 512-bit candidate mask per pixel
  __shared__ float Xs[PXB];           // np-exact ||x||^2 per pixel
  __shared__ int sidx[PXB];
  __shared__ float sredf[8];

  const int tid = threadIdx.x;
  const int lane = tid & 63;
  const int wv = tid >> 6;            // wave 0..7, each owns 16 pixels
  const int cn = lane & 15;           // C-layout col (code within tile)

  // tile A = blockIdx.x, tile B = blockIdx.x + 512
  const int bix0 = blockIdx.x;
  const int b0 = bix0 >> 5;
  const int q0 = (bix0 & 31) * PXB;
  const float* xt0 = x + (size_t)b0 * (DD * HW) + q0;
  const int bix1 = blockIdx.x + NBLK;
  const int b1 = bix1 >> 5;
  const int q1 = (bix1 & 31) * PXB;
  const float* xt1 = x + (size_t)b1 * (DD * HW) + q1;

  w2s[tid] = w2g[tid];   // KC == NTH

  unsigned p[64];        // packed bf16 screen dists (constant-indexed only)
  short8 a0, a1;
  tile_prelude(xt0, Xs, candm, a0, a1, tid, lane, wv);
  __syncthreads();       // w2s/candm/Xs ready

  // ================= TILE A =================
  SCREEN_AND_FLAG(a0, a1)
  barrier_lds_only();    // candm-A ready
  tile_refine(xt0, w, w2s, Xs, candm, sidx, out_idx, bix0, tid, lane);
  barrier_lds_only();    // sidx-A ready; all waves past refine-A

  // prelude-B FIRST (loads issue before the A-output store burst; overwrites
  // Xs/candm — safe, refine-A done), then A outputs (stores last).
  tile_prelude(xt1, Xs, candm, a0, a1, tid, lane, wv);
  {
    float lsum = tile_quant(xt0, w, sidx, out_q + (size_t)b0 * (DD * HW) + q0, tid);
    #pragma unroll
    for (int off = 32; off > 0; off >>= 1) lsum += __shfl_down(lsum, off);
    if (lane == 0) sredf[wv] = lsum;
  }
  tile_enc(sidx, out_enc + (size_t)bix0 * (PXB * KC), tid);
  barrier_lds_only();    // sredf/Xs-B/candm-B ready; A stores stay in flight
  if (tid == 0) {
    double t = 0.0;
    #pragma unroll
    for (int i = 0; i < 8; ++i) t += (double)sredf[i];
    partial[bix0] = t;
  }

  // ================= TILE B =================
  SCREEN_AND_FLAG(a0, a1)   // A-output stores drain under this sweep
  barrier_lds_only();    // candm-B ready
  tile_refine(xt1, w, w2s, Xs, candm, sidx, out_idx, bix1, tid, lane);
  barrier_lds_only();    // sidx-B ready
  {
    float lsum = tile_quant(xt1, w, sidx, out_q + (size_t)b1 * (DD * HW) + q1, tid);
    #pragma unroll
    for (int off = 32; off > 0; off >>= 1) lsum += __shfl_down(lsum, off);
    if (lane == 0) sredf[wv] = lsum;
  }
  tile_enc(sidx, out_enc + (size_t)bix1 * (PXB * KC), tid);
  barrier_lds_only();    // sredf-B ready
  if (tid == 0) {
    double t = 0.0;
    #pragma unroll
    for (int i = 0; i < 8; ++i) t += (double)sredf[i];
    partial[bix1] = t;
  }
  // kernel end: implicit full drain of tile-B stores
}

// --- epilogue: loss = vq + commit = 2 * mean((q - x)^2) ---
__global__ void finish_kernel(const double* __restrict__ partial,
                              float* __restrict__ out) {
  int t = threadIdx.x;   // 256 threads, 1024 partials
  double s = partial[t] + partial[t + 256] + partial[t + 512] + partial[t + 768];
  #pragma unroll
  for (int off = 32; off > 0; off >>= 1) s += __shfl_down(s, off);
  __shared__ double sr[4];
  if ((t & 63) == 0) sr[t >> 6] = s;
  __syncthreads();
  if (t == 0)
    out[0] = (float)(2.0 * (sr[0] + sr[1] + sr[2] + sr[3]) / (double)QSIZE);
}

extern "C" void kernel_launch(void* const* d_in, const int* in_sizes, int n_in,
                              void* d_out, int out_size, void* d_ws, size_t ws_size,
                              hipStream_t stream) {
  const float* x = (const float*)d_in[0];   // [32,64,64,64] f32 NCHW
  const float* w = (const float*)d_in[1];   // [512,64] f32
  float* out = (float*)d_out;
  float* out_q = out + 1;
  float* out_enc = out_q + QSIZE;
  float* out_idx = out_enc + (size_t)NPIX * KC;

  // d_ws layout: partial[1024] @0 (8 KB) | w2g[512] @8192 | wswz[4096] @16384
  double* partial = (double*)d_ws;
  float* w2g = (float*)((char*)d_ws + 8192);
  uint4* wswz = (uint4*)((char*)d_ws + 16384);

  prep<<<4, 1024, 0, stream>>>(w, w2g, wswz);
  vq_fused<<<NBLK, NTH, 0, stream>>>(x, w, w2g, (const short8*)wswz,
                                     out_q, out_enc, out_idx, partial);
  finish_kernel<<<1, 256, 0, stream>>>(partial, out);
}

// Round 7
// 464.131 us; speedup vs baseline: 1.0658x; 1.0658x over previous
//
#include <hip/hip_runtime.h>
#include <cfloat>

#define KC 512        // codes
#define DD 64         // dim
#define HW 4096       // 64*64
#define NPIX 131072   // 32*64*64
#define QSIZE 8388608 // 32*64*64*64
#define PXB 128       // pixels per block
#define NBLK (NPIX / PXB)  // 1024 blocks = one full-chip round at 4 blocks/CU
#define NTH 512       // 8 waves
#define MARGIN 4.0e-3f  // >6x worst-case screen-vs-np error bound

typedef short short8 __attribute__((ext_vector_type(8)));   // 8 bf16 MFMA operand
typedef float f32x4 __attribute__((ext_vector_type(4)));
typedef float nfloat4 __attribute__((ext_vector_type(4)));
typedef unsigned long long u64;

__device__ __forceinline__ unsigned short bf16_rne(float f) {
    unsigned int u = __float_as_uint(f);
    u += 0x7FFFu + ((u >> 16) & 1u);
    return (unsigned short)(u >> 16);
}

// LDS-only barrier: syncs waves + orders DS ops without draining vmcnt —
// in-flight NT output stores keep streaming across it. Legal: no global RAW
// anywhere in this kernel (all global writes go to write-only outputs).
__device__ __forceinline__ void barrier_lds_only() {
    asm volatile("s_waitcnt lgkmcnt(0)" ::: "memory");
    __builtin_amdgcn_s_barrier();
    __builtin_amdgcn_sched_barrier(0);
}

// --- prep (once per launch, validated R10): swizzled bf16 B-frag codebook
// (64 KB) + np-pairwise w2. Slot s=(ct*2+kc)*64+ln holds
// w[ct*16+(ln&15)][kc*32+(ln>>4)*8 .. +8) as bf16x8.
__global__ __launch_bounds__(1024) void prep(
    const float* __restrict__ w, float* __restrict__ w2g,
    uint4* __restrict__ wswz) {
  const int gt = blockIdx.x * 1024 + threadIdx.x;   // 0..4095
  {
    int ct = gt >> 7, kc = (gt >> 6) & 1, ln = gt & 63;
    int n = ln & 15, q = ln >> 4;
    const float* wp = w + (ct * 16 + n) * DD + kc * 32 + q * 8;
    nfloat4 f0 = *(const nfloat4*)(wp);
    nfloat4 f1 = *(const nfloat4*)(wp + 4);
    uint4 u;
    u.x = (unsigned)bf16_rne(f0[0]) | ((unsigned)bf16_rne(f0[1]) << 16);
    u.y = (unsigned)bf16_rne(f0[2]) | ((unsigned)bf16_rne(f0[3]) << 16);
    u.z = (unsigned)bf16_rne(f1[0]) | ((unsigned)bf16_rne(f1[1]) << 16);
    u.w = (unsigned)bf16_rne(f1[2]) | ((unsigned)bf16_rne(f1[3]) << 16);
    wswz[gt] = u;
  }
  if (gt < KC) {      // w2g[k]: numpy-pairwise fp32 sum of squares
    const float* wk = w + gt * DD;
    float r0 = __fmul_rn(wk[0], wk[0]), r1 = __fmul_rn(wk[1], wk[1]),
          r2 = __fmul_rn(wk[2], wk[2]), r3 = __fmul_rn(wk[3], wk[3]),
          r4 = __fmul_rn(wk[4], wk[4]), r5 = __fmul_rn(wk[5], wk[5]),
          r6 = __fmul_rn(wk[6], wk[6]), r7 = __fmul_rn(wk[7], wk[7]);
    #pragma unroll
    for (int i = 8; i < DD; i += 8) {
      r0 = __fadd_rn(r0, __fmul_rn(wk[i+0], wk[i+0]));
      r1 = __fadd_rn(r1, __fmul_rn(wk[i+1], wk[i+1]));
      r2 = __fadd_rn(r2, __fmul_rn(wk[i+2], wk[i+2]));
      r3 = __fadd_rn(r3, __fmul_rn(wk[i+3], wk[i+3]));
      r4 = __fadd_rn(r4, __fmul_rn(wk[i+4], wk[i+4]));
      r5 = __fadd_rn(r5, __fmul_rn(wk[i+5], wk[i+5]));
      r6 = __fadd_rn(r6, __fmul_rn(wk[i+6], wk[i+6]));
      r7 = __fadd_rn(r7, __fmul_rn(wk[i+7], wk[i+7]));
    }
    w2g[gt] = __fadd_rn(__fadd_rn(__fadd_rn(r0, r1), __fadd_rn(r2, r3)),
                        __fadd_rn(__fadd_rn(r4, r5), __fadd_rn(r6, r7)));
  }
}

// --- main R17: R0's proven single-tile flow + two-pass screen, but with the
// LDS codebook DROPPED (B-frags stream from L2-resident wswz) so LDS falls
// 75 KB -> 11 KB, and __launch_bounds__(512, 8) caps VGPR at 64 (R6's counter
// shows the non-spilled body fits) -> 4 blocks/CU, 32 waves/CU = 100%
// occupancy (was 43%). Latency-bound phases (R6 PMC: MfmaUtil 1.6%, VALU 17%,
// HBM 43%) get 2x the waves; each retiring block's NT store drain overlaps 3
// co-resident blocks' compute. Numerics bit-identical to R0/R4.
__global__ __launch_bounds__(NTH, 8) void vq_fused(
    const float* __restrict__ x, const float* __restrict__ w,
    const float* __restrict__ w2g, const short8* __restrict__ wsw8,
    float* __restrict__ out_q, float* __restrict__ out_enc,
    float* __restrict__ out_idx, double* __restrict__ partial) {

  __shared__ float w2s[KC];           // 2 KB: np-exact ||w_k||^2
  __shared__ u64 candm[PXB][8];       // 8 KB: 512-bit candidate mask per pixel
  __shared__ float Xs[PXB];           // np-exact ||x||^2 per pixel
  __shared__ int sidx[PXB];
  __shared__ float sredf[8];

  const int tid = threadIdx.x;
  const int lane = tid & 63;
  const int wv = tid >> 6;            // wave 0..7, each owns 16 pixels
  const int cn = lane & 15;           // C-layout col (code within tile)
  const int bix = blockIdx.x;
  const int b = bix >> 5;             // 32 blocks per image (4096/128)
  const int p0 = (bix & 31) * PXB;
  const float* xt = x + (size_t)b * (DD * HW) + p0;   // this block's x tile

  // ---- tiny LDS staging: w2 (2 KB) + candm zero ----
  w2s[tid] = w2g[tid];                // KC == NTH
  ((u64*)candm)[tid] = 0;
  ((u64*)candm)[tid + NTH] = 0;

  // ---- Xs: np-pairwise ||x||^2 from global x (one px per thread) ----
  if (tid < PXB) {
    const float* xp = xt + tid;
    float r0 = __fmul_rn(xp[0*HW], xp[0*HW]), r1 = __fmul_rn(xp[1*HW], xp[1*HW]),
          r2 = __fmul_rn(xp[2*HW], xp[2*HW]), r3 = __fmul_rn(xp[3*HW], xp[3*HW]),
          r4 = __fmul_rn(xp[4*HW], xp[4*HW]), r5 = __fmul_rn(xp[5*HW], xp[5*HW]),
          r6 = __fmul_rn(xp[6*HW], xp[6*HW]), r7 = __fmul_rn(xp[7*HW], xp[7*HW]);
    #pragma unroll
    for (int i = 8; i < DD; i += 8) {
      r0 = __fadd_rn(r0, __fmul_rn(xp[(size_t)(i+0)*HW], xp[(size_t)(i+0)*HW]));
      r1 = __fadd_rn(r1, __fmul_rn(xp[(size_t)(i+1)*HW], xp[(size_t)(i+1)*HW]));
      r2 = __fadd_rn(r2, __fmul_rn(xp[(size_t)(i+2)*HW], xp[(size_t)(i+2)*HW]));
      r3 = __fadd_rn(r3, __fmul_rn(xp[(size_t)(i+3)*HW], xp[(size_t)(i+3)*HW]));
      r4 = __fadd_rn(r4, __fmul_rn(xp[(size_t)(i+4)*HW], xp[(size_t)(i+4)*HW]));
      r5 = __fadd_rn(r5, __fmul_rn(xp[(size_t)(i+5)*HW], xp[(size_t)(i+5)*HW]));
      r6 = __fadd_rn(r6, __fmul_rn(xp[(size_t)(i+6)*HW], xp[(size_t)(i+6)*HW]));
      r7 = __fadd_rn(r7, __fmul_rn(xp[(size_t)(i+7)*HW], xp[(size_t)(i+7)*HW]));
    }
    Xs[tid] = __fadd_rn(__fadd_rn(__fadd_rn(r0, r1), __fadd_rn(r2, r3)),
                        __fadd_rn(__fadd_rn(r4, r5), __fadd_rn(r6, r7)));
  }

  // ---- A-frags from global x: A[m=lane&15][k=quad*8+j] of (-2x), bf16 ----
  const int am = lane & 15, aq = lane >> 4;
  const float* xa = xt + wv * 16 + am;
  short8 a0, a1;
  #pragma unroll
  for (int j = 0; j < 8; ++j) {
    a0[j] = (short)bf16_rne(-2.0f * xa[(size_t)(aq * 8 + j) * HW]);
    a1[j] = (short)bf16_rne(-2.0f * xa[(size_t)(32 + aq * 8 + j) * HW]);
  }

  __syncthreads();   // w2s + candm + Xs ready

  // ---- pass 1: per-pixel min of screened S over 512 codes, B from L2 ----
  // C layout (m89-verified): col=lane&15, row=(lane>>4)*4+reg
  float m0 = FLT_MAX, m1 = FLT_MAX, m2 = FLT_MAX, m3 = FLT_MAX;
  for (int ct = 0; ct < 32; ++ct) {
    float wk2 = w2s[ct * 16 + cn];
    short8 b0 = wsw8[ct * 128 + lane];
    short8 b1 = wsw8[ct * 128 + 64 + lane];
    f32x4 acc = {wk2, wk2, wk2, wk2};
    acc = __builtin_amdgcn_mfma_f32_16x16x32_bf16(a0, b0, acc, 0, 0, 0);
    acc = __builtin_amdgcn_mfma_f32_16x16x32_bf16(a1, b1, acc, 0, 0, 0);
    m0 = fminf(m0, acc[0]); m1 = fminf(m1, acc[1]);
    m2 = fminf(m2, acc[2]); m3 = fminf(m3, acc[3]);
  }
  #pragma unroll
  for (int s = 1; s < 16; s <<= 1) {
    m0 = fminf(m0, __shfl_xor(m0, s));
    m1 = fminf(m1, __shfl_xor(m1, s));
    m2 = fminf(m2, __shfl_xor(m2, s));
    m3 = fminf(m3, __shfl_xor(m3, s));
  }
  const float t0 = m0 + MARGIN, t1 = m1 + MARGIN,
              t2 = m2 + MARGIN, t3 = m3 + MARGIN;

  // ---- pass 2: flag candidates into per-pixel bitmasks ----
  for (int ct = 0; ct < 32; ++ct) {
    float wk2 = w2s[ct * 16 + cn];
    short8 b0 = wsw8[ct * 128 + lane];
    short8 b1 = wsw8[ct * 128 + 64 + lane];
    f32x4 acc = {wk2, wk2, wk2, wk2};
    acc = __builtin_amdgcn_mfma_f32_16x16x32_bf16(a0, b0, acc, 0, 0, 0);
    acc = __builtin_amdgcn_mfma_f32_16x16x32_bf16(a1, b1, acc, 0, 0, 0);
    u64 bm0 = __ballot(acc[0] <= t0);
    u64 bm1 = __ballot(acc[1] <= t1);
    u64 bm2 = __ballot(acc[2] <= t2);
    u64 bm3 = __ballot(acc[3] <= t3);
    if (lane < 4) {   // lane r owns reg r; ballot bit (q*16+n) -> pixel q*4+r, code ct*16+n
      u64 mk = (lane == 0) ? bm0 : (lane == 1) ? bm1 : (lane == 2) ? bm2 : bm3;
      int word = ct >> 2, sh = (ct & 3) * 16;
      #pragma unroll
      for (int q = 0; q < 4; ++q) {
        u64 bits = (mk >> (q * 16)) & 0xFFFFull;
        if (bits) candm[wv * 16 + q * 4 + lane][word] |= bits << sh;
      }
    }
  }
  barrier_lds_only();   // candm ready

  // ---- refine: 4 threads per pixel, exact np fp32 dist over candidates ----
  {
    const int px = tid >> 2, part = tid & 3;
    const float X = Xs[px];
    const float* xr = xt + px;
    float bestd = FLT_MAX; int bk = 1 << 30;
    for (int wd = part * 2; wd < part * 2 + 2; ++wd) {
      u64 msk = candm[px][wd];
      while (msk) {
        int bit = __ffsll((unsigned long long)msk) - 1;
        msk &= msk - 1;
        int k = wd * 64 + bit;
        const float* wp = w + k * DD;
        float P = 0.f;                       // ascending-d fma chain (BLAS order)
        #pragma unroll
        for (int dc = 0; dc < 16; ++dc) {
          nfloat4 w4 = *(const nfloat4*)(wp + dc * 4);
          P = __fmaf_rn(xr[(size_t)(dc * 4 + 0) * HW], w4[0], P);
          P = __fmaf_rn(xr[(size_t)(dc * 4 + 1) * HW], w4[1], P);
          P = __fmaf_rn(xr[(size_t)(dc * 4 + 2) * HW], w4[2], P);
          P = __fmaf_rn(xr[(size_t)(dc * 4 + 3) * HW], w4[3], P);
        }
        float dist = __fsub_rn(__fadd_rn(X, w2s[k]), __fadd_rn(P, P));
        if (dist < bestd || (dist == bestd && k < bk)) { bestd = dist; bk = k; }
      }
    }
    // merge the 4 parts (tie -> smaller k, matching np.argmin first-index)
    float od = __shfl_down(bestd, 1); int ok = __shfl_down(bk, 1);
    if ((lane & 3) < 3 && (od < bestd || (od == bestd && ok < bk))) { bestd = od; bk = ok; }
    od = __shfl_down(bestd, 2); ok = __shfl_down(bk, 2);
    if ((lane & 3) < 2 && (od < bestd || (od == bestd && ok < bk))) { bestd = od; bk = ok; }
    if (part == 0) {
      sidx[px] = bk;
      out_idx[bix * PXB + px] = (float)bk;
    }
  }
  barrier_lds_only();   // sidx ready

  // ---- quant (coalesced 256B rows) + loss ----
  float lsum = 0.f;
  float* qb = out_q + (size_t)b * (DD * HW) + p0;
  for (int i = tid; i < PXB * DD; i += NTH) {   // 16 iters
    int d = i >> 7, pp = i & 127;
    float qv = w[sidx[pp] * DD + d];      // L1/L2-resident gather
    float dv = qv - xt[(size_t)d * HW + pp];
    lsum = __fmaf_rn(dv, dv, lsum);
    __builtin_nontemporal_store(qv, qb + (size_t)d * HW + pp);
  }
  #pragma unroll
  for (int off = 32; off > 0; off >>= 1) lsum += __shfl_down(lsum, off);
  if (lane == 0) sredf[wv] = lsum;

  // ---- one-hot enc (base ≡ 1 mod 4 floats: 3-head, aligned body, 1-tail) ----
  float* basep = out_enc + (size_t)bix * (PXB * KC);
  for (int t = tid; t < 16383; t += NTH) {
    int u = 3 + 4 * t;
    nfloat4 v;
    #pragma unroll
    for (int j = 0; j < 4; ++j) {
      int e = u + j;
      v[j] = (sidx[e >> 9] == (e & 511)) ? 1.0f : 0.0f;
    }
    __builtin_nontemporal_store(v, (nfloat4*)(basep + u));
  }
  if (tid < 3) basep[tid] = (sidx[0] == tid) ? 1.0f : 0.0f;
  else if (tid == 3) basep[PXB * KC - 1] = (sidx[127] == 511) ? 1.0f : 0.0f;

  barrier_lds_only();   // sredf ready (stores keep draining)
  if (tid == 0) {
    double t = 0.0;
    #pragma unroll
    for (int i = 0; i < 8; ++i) t += (double)sredf[i];
    partial[bix] = t;
  }
  // endpgm drain overlaps the 3 co-resident blocks' compute
}

// --- epilogue: loss = vq + commit = 2 * mean((q - x)^2) ---
__global__ void finish_kernel(const double* __restrict__ partial,
                              float* __restrict__ out) {
  int t = threadIdx.x;   // 256 threads, 1024 partials
  double s = partial[t] + partial[t + 256] + partial[t + 512] + partial[t + 768];
  #pragma unroll
  for (int off = 32; off > 0; off >>= 1) s += __shfl_down(s, off);
  __shared__ double sr[4];
  if ((t & 63) == 0) sr[t >> 6] = s;
  __syncthreads();
  if (t == 0)
    out[0] = (float)(2.0 * (sr[0] + sr[1] + sr[2] + sr[3]) / (double)QSIZE);
}

extern "C" void kernel_launch(void* const* d_in, const int* in_sizes, int n_in,
                              void* d_out, int out_size, void* d_ws, size_t ws_size,
                              hipStream_t stream) {
  const float* x = (const float*)d_in[0];   // [32,64,64,64] f32 NCHW
  const float* w = (const float*)d_in[1];   // [512,64] f32
  float* out = (float*)d_out;
  float* out_q = out + 1;
  float* out_enc = out_q + QSIZE;
  float* out_idx = out_enc + (size_t)NPIX * KC;

  // d_ws layout: partial[1024] @0 (8 KB) | w2g[512] @8192 | wswz[4096] @16384
  double* partial = (double*)d_ws;
  float* w2g = (float*)((char*)d_ws + 8192);
  uint4* wswz = (uint4*)((char*)d_ws + 16384);

  prep<<<4, 1024, 0, stream>>>(w, w2g, wswz);
  vq_fused<<<NBLK, NTH, 0, stream>>>(x, w, w2g, (const short8*)wswz,
                                     out_q, out_enc, out_idx, partial);
  finish_kernel<<<1, 256, 0, stream>>>(partial, out);
}

// Round 8
// 403.738 us; speedup vs baseline: 1.2252x; 1.1496x over previous
//
#include <hip/hip_runtime.h>
#include <cfloat>

#define KC 512        // codes
#define DD 64         // dim
#define HW 4096       // 64*64
#define NPIX 131072   // 32*64*64
#define QSIZE 8388608 // 32*64*64*64
#define PXB 128       // pixels per tile
#define NTILE (NPIX / PXB)   // 1024 tiles
#define NBLK (NTILE / 2)     // 512 persistent blocks, 2 tiles each
#define NTH 512       // 8 waves
#define MARGIN 4.0e-3f  // >6x worst-case screen-vs-np error bound

typedef short short8 __attribute__((ext_vector_type(8)));   // 8 bf16 MFMA operand
typedef float f32x4 __attribute__((ext_vector_type(4)));
typedef float nfloat4 __attribute__((ext_vector_type(4)));
typedef unsigned long long u64;

__device__ __forceinline__ unsigned short bf16_rne(float f) {
    unsigned int u = __float_as_uint(f);
    u += 0x7FFFu + ((u >> 16) & 1u);
    return (unsigned short)(u >> 16);
}

// In-wave LDS fence: waits for this wave's own DS ops (cross-LANE visibility
// within the wave). NOT a block barrier — waves run fully independently.
__device__ __forceinline__ void wave_fence() {
    asm volatile("s_waitcnt lgkmcnt(0)" ::: "memory");
}

// --- prep (once per launch, validated R10): swizzled bf16 B-frag codebook
// (64 KB) + np-pairwise w2. Slot s=(ct*2+kc)*64+ln holds
// w[ct*16+(ln&15)][kc*32+(ln>>4)*8 .. +8) as bf16x8.
__global__ __launch_bounds__(1024) void prep(
    const float* __restrict__ w, float* __restrict__ w2g,
    uint4* __restrict__ wswz) {
  const int gt = blockIdx.x * 1024 + threadIdx.x;   // 0..4095
  {
    int ct = gt >> 7, kc = (gt >> 6) & 1, ln = gt & 63;
    int n = ln & 15, q = ln >> 4;
    const float* wp = w + (ct * 16 + n) * DD + kc * 32 + q * 8;
    nfloat4 f0 = *(const nfloat4*)(wp);
    nfloat4 f1 = *(const nfloat4*)(wp + 4);
    uint4 u;
    u.x = (unsigned)bf16_rne(f0[0]) | ((unsigned)bf16_rne(f0[1]) << 16);
    u.y = (unsigned)bf16_rne(f0[2]) | ((unsigned)bf16_rne(f0[3]) << 16);
    u.z = (unsigned)bf16_rne(f1[0]) | ((unsigned)bf16_rne(f1[1]) << 16);
    u.w = (unsigned)bf16_rne(f1[2]) | ((unsigned)bf16_rne(f1[3]) << 16);
    wswz[gt] = u;
  }
  if (gt < KC) {      // w2g[k]: numpy-pairwise fp32 sum of squares
    const float* wk = w + gt * DD;
    float r0 = __fmul_rn(wk[0], wk[0]), r1 = __fmul_rn(wk[1], wk[1]),
          r2 = __fmul_rn(wk[2], wk[2]), r3 = __fmul_rn(wk[3], wk[3]),
          r4 = __fmul_rn(wk[4], wk[4]), r5 = __fmul_rn(wk[5], wk[5]),
          r6 = __fmul_rn(wk[6], wk[6]), r7 = __fmul_rn(wk[7], wk[7]);
    #pragma unroll
    for (int i = 8; i < DD; i += 8) {
      r0 = __fadd_rn(r0, __fmul_rn(wk[i+0], wk[i+0]));
      r1 = __fadd_rn(r1, __fmul_rn(wk[i+1], wk[i+1]));
      r2 = __fadd_rn(r2, __fmul_rn(wk[i+2], wk[i+2]));
      r3 = __fadd_rn(r3, __fmul_rn(wk[i+3], wk[i+3]));
      r4 = __fadd_rn(r4, __fmul_rn(wk[i+4], wk[i+4]));
      r5 = __fadd_rn(r5, __fmul_rn(wk[i+5], wk[i+5]));
      r6 = __fadd_rn(r6, __fmul_rn(wk[i+6], wk[i+6]));
      r7 = __fadd_rn(r7, __fmul_rn(wk[i+7], wk[i+7]));
    }
    w2g[gt] = __fadd_rn(__fadd_rn(__fadd_rn(r0, r1), __fadd_rn(r2, r3)),
                        __fadd_rn(__fadd_rn(r4, r5), __fadd_rn(r6, r7)));
  }
}

// ---- one tile's full pipeline for ONE WAVE (16 pixels), no block barriers.
// Phase bodies numerically identical to the R0/R4 kernel; only the thread->
// work mapping of Xs/quant/enc is re-partitioned per-wave (same arithmetic
// per pixel; loss f32-partial grouping differs by ~1e-8 relative).
__device__ __forceinline__ void wave_tile(
    const float* __restrict__ xt, const float* __restrict__ w,
    const float* w2s, const short8* wl8,
    u64 (*candm)[8], float* Xs, int* sidx,
    float* __restrict__ qb, float* __restrict__ bp,
    float* __restrict__ out_idx, double* __restrict__ partial,
    int bix, int lane, int wv) {

  // ---- wave-private prelude: zero candm, Xs (np-exact), A-frags ----
  {
    u64* cz = (u64*)(candm + wv * 16);   // wave's 128 u64
    cz[lane] = 0;
    cz[lane + 64] = 0;
  }
  if (lane < 16) {
    const float* xp = xt + wv * 16 + lane;
    float r0 = __fmul_rn(xp[0*HW], xp[0*HW]), r1 = __fmul_rn(xp[1*HW], xp[1*HW]),
          r2 = __fmul_rn(xp[2*HW], xp[2*HW]), r3 = __fmul_rn(xp[3*HW], xp[3*HW]),
          r4 = __fmul_rn(xp[4*HW], xp[4*HW]), r5 = __fmul_rn(xp[5*HW], xp[5*HW]),
          r6 = __fmul_rn(xp[6*HW], xp[6*HW]), r7 = __fmul_rn(xp[7*HW], xp[7*HW]);
    #pragma unroll
    for (int i = 8; i < DD; i += 8) {
      r0 = __fadd_rn(r0, __fmul_rn(xp[(size_t)(i+0)*HW], xp[(size_t)(i+0)*HW]));
      r1 = __fadd_rn(r1, __fmul_rn(xp[(size_t)(i+1)*HW], xp[(size_t)(i+1)*HW]));
      r2 = __fadd_rn(r2, __fmul_rn(xp[(size_t)(i+2)*HW], xp[(size_t)(i+2)*HW]));
      r3 = __fadd_rn(r3, __fmul_rn(xp[(size_t)(i+3)*HW], xp[(size_t)(i+3)*HW]));
      r4 = __fadd_rn(r4, __fmul_rn(xp[(size_t)(i+4)*HW], xp[(size_t)(i+4)*HW]));
      r5 = __fadd_rn(r5, __fmul_rn(xp[(size_t)(i+5)*HW], xp[(size_t)(i+5)*HW]));
      r6 = __fadd_rn(r6, __fmul_rn(xp[(size_t)(i+6)*HW], xp[(size_t)(i+6)*HW]));
      r7 = __fadd_rn(r7, __fmul_rn(xp[(size_t)(i+7)*HW], xp[(size_t)(i+7)*HW]));
    }
    Xs[wv * 16 + lane] =
        __fadd_rn(__fadd_rn(__fadd_rn(r0, r1), __fadd_rn(r2, r3)),
                  __fadd_rn(__fadd_rn(r4, r5), __fadd_rn(r6, r7)));
  }
  const int am = lane & 15, aq = lane >> 4;
  const float* xa = xt + wv * 16 + am;
  short8 a0, a1;
  #pragma unroll
  for (int j = 0; j < 8; ++j) {
    a0[j] = (short)bf16_rne(-2.0f * xa[(size_t)(aq * 8 + j) * HW]);
    a1[j] = (short)bf16_rne(-2.0f * xa[(size_t)(32 + aq * 8 + j) * HW]);
  }
  wave_fence();   // candm zeros + Xs visible to whole wave

  const int cn = lane & 15;   // C-layout col (code within tile)

  // ---- pass 1: per-pixel min of screened S over 512 codes ----
  // C layout (m89-verified): col=lane&15, row=(lane>>4)*4+reg
  float m0 = FLT_MAX, m1 = FLT_MAX, m2 = FLT_MAX, m3 = FLT_MAX;
  for (int ct = 0; ct < 32; ++ct) {
    float wk2 = w2s[ct * 16 + cn];
    f32x4 acc = {wk2, wk2, wk2, wk2};
    acc = __builtin_amdgcn_mfma_f32_16x16x32_bf16(a0, wl8[ct * 128 + lane], acc, 0, 0, 0);
    acc = __builtin_amdgcn_mfma_f32_16x16x32_bf16(a1, wl8[ct * 128 + 64 + lane], acc, 0, 0, 0);
    m0 = fminf(m0, acc[0]); m1 = fminf(m1, acc[1]);
    m2 = fminf(m2, acc[2]); m3 = fminf(m3, acc[3]);
  }
  #pragma unroll
  for (int s = 1; s < 16; s <<= 1) {
    m0 = fminf(m0, __shfl_xor(m0, s));
    m1 = fminf(m1, __shfl_xor(m1, s));
    m2 = fminf(m2, __shfl_xor(m2, s));
    m3 = fminf(m3, __shfl_xor(m3, s));
  }
  const float t0 = m0 + MARGIN, t1 = m1 + MARGIN,
              t2 = m2 + MARGIN, t3 = m3 + MARGIN;

  // ---- pass 2: flag candidates into wave-private bitmasks ----
  for (int ct = 0; ct < 32; ++ct) {
    float wk2 = w2s[ct * 16 + cn];
    f32x4 acc = {wk2, wk2, wk2, wk2};
    acc = __builtin_amdgcn_mfma_f32_16x16x32_bf16(a0, wl8[ct * 128 + lane], acc, 0, 0, 0);
    acc = __builtin_amdgcn_mfma_f32_16x16x32_bf16(a1, wl8[ct * 128 + 64 + lane], acc, 0, 0, 0);
    u64 bm0 = __ballot(acc[0] <= t0);
    u64 bm1 = __ballot(acc[1] <= t1);
    u64 bm2 = __ballot(acc[2] <= t2);
    u64 bm3 = __ballot(acc[3] <= t3);
    if (lane < 4) {   // lane r owns reg r; ballot bit (q*16+n) -> pixel q*4+r, code ct*16+n
      u64 mk = (lane == 0) ? bm0 : (lane == 1) ? bm1 : (lane == 2) ? bm2 : bm3;
      int word = ct >> 2, sh = (ct & 3) * 16;
      #pragma unroll
      for (int q = 0; q < 4; ++q) {
        u64 bits = (mk >> (q * 16)) & 0xFFFFull;
        if (bits) candm[wv * 16 + q * 4 + lane][word] |= bits << sh;
      }
    }
  }
  wave_fence();   // candm ready for this wave

  // ---- refine: 4 lanes per pixel, exact np fp32 dist over candidates ----
  {
    const int px = wv * 16 + (lane >> 2), part = lane & 3;
    const float X = Xs[px];
    const float* xr = xt + px;
    float bestd = FLT_MAX; int bk = 1 << 30;
    for (int wd = part * 2; wd < part * 2 + 2; ++wd) {
      u64 msk = candm[px][wd];
      while (msk) {
        int bit = __ffsll((unsigned long long)msk) - 1;
        msk &= msk - 1;
        int k = wd * 64 + bit;
        const float* wp = w + k * DD;
        float P = 0.f;                       // ascending-d fma chain (BLAS order)
        #pragma unroll
        for (int dc = 0; dc < 16; ++dc) {
          nfloat4 w4 = *(const nfloat4*)(wp + dc * 4);
          P = __fmaf_rn(xr[(size_t)(dc * 4 + 0) * HW], w4[0], P);
          P = __fmaf_rn(xr[(size_t)(dc * 4 + 1) * HW], w4[1], P);
          P = __fmaf_rn(xr[(size_t)(dc * 4 + 2) * HW], w4[2], P);
          P = __fmaf_rn(xr[(size_t)(dc * 4 + 3) * HW], w4[3], P);
        }
        float dist = __fsub_rn(__fadd_rn(X, w2s[k]), __fadd_rn(P, P));
        if (dist < bestd || (dist == bestd && k < bk)) { bestd = dist; bk = k; }
      }
    }
    // merge the 4 parts (tie -> smaller k, matching np.argmin first-index)
    float od = __shfl_down(bestd, 1); int ok = __shfl_down(bk, 1);
    if ((lane & 3) < 3 && (od < bestd || (od == bestd && ok < bk))) { bestd = od; bk = ok; }
    od = __shfl_down(bestd, 2); ok = __shfl_down(bk, 2);
    if ((lane & 3) < 2 && (od < bestd || (od == bestd && ok < bk))) { bestd = od; bk = ok; }
    if (part == 0) {
      sidx[px] = bk;
      out_idx[bix * PXB + px] = (float)bk;
    }
  }
  wave_fence();   // sidx ready for this wave

  // ---- quant (wave's 16 px) + loss ----
  const int ppl = wv * 16 + (lane & 15);
  const int kk = sidx[ppl];
  const int dbase = lane >> 4;           // 0..3
  float lsum = 0.f;
  #pragma unroll
  for (int it = 0; it < 16; ++it) {
    int d = dbase + it * 4;
    float qv = w[kk * DD + d];           // L1/L2-resident gather
    float dv = qv - xt[(size_t)d * HW + ppl];
    lsum = __fmaf_rn(dv, dv, lsum);
    __builtin_nontemporal_store(qv, qb + (size_t)d * HW + ppl);
  }

  // ---- one-hot enc: wave region = 16 px * 512 = 8192 floats, global base
  // ≡ 1 mod 4 -> 3-head, 2047 aligned f32x4 body, 1-tail ----
  for (int t = lane; t < 2047; t += 64) {
    int u = 3 + 4 * t;
    int e = wv * 8192 + u;
    nfloat4 v;
    #pragma unroll
    for (int j = 0; j < 4; ++j) {
      int ej = e + j;
      v[j] = (sidx[ej >> 9] == (ej & 511)) ? 1.0f : 0.0f;
    }
    __builtin_nontemporal_store(v, (nfloat4*)(bp + u));
  }
  if (lane < 3) bp[lane] = (sidx[wv * 16] == lane) ? 1.0f : 0.0f;
  else if (lane == 3) bp[8191] = (sidx[wv * 16 + 15] == 511) ? 1.0f : 0.0f;

  // ---- per-wave loss partial ----
  #pragma unroll
  for (int off = 32; off > 0; off >>= 1) lsum += __shfl_down(lsum, off);
  if (lane == 0) partial[bix * 8 + wv] = (double)lsum;
}

// --- main R18: barrier-free waves. One __syncthreads after codebook staging,
// then each wave independently runs prelude->screen->refine->quant->enc for
// its 16 pixels of tile A, then tile B. All inter-phase waits are in-wave
// lgkmcnt fences; slow-wave stalls overlap other waves' compute instead of
// convoying 8 waves x 6 phases (R6/R7 PMC: nothing saturated at any occupancy
// -> serialization-bound). Phase numerics identical to R0/R4.
__global__ __launch_bounds__(NTH, 4) void vq_fused(
    const float* __restrict__ x, const float* __restrict__ w,
    const float* __restrict__ w2g, const uint4* __restrict__ wswz,
    float* __restrict__ out_q, float* __restrict__ out_enc,
    float* __restrict__ out_idx, double* __restrict__ partial) {

  __shared__ uint4 wlds[4096];        // 64 KB: B-frags, slot=(ct*2+kc)*64+lane
  __shared__ float w2s[KC];           // 2 KB: np-exact ||w_k||^2
  __shared__ u64 candm[PXB][8];       // 8 KB: wave-private candidate masks
  __shared__ float Xs[PXB];           // wave-private ||x||^2
  __shared__ int sidx[PXB];           // wave-private winners

  const int tid = threadIdx.x;
  const int lane = tid & 63;
  const int wv = tid >> 6;            // wave 0..7, each owns 16 pixels

  // tile A = blockIdx.x, tile B = blockIdx.x + 512
  const int bix0 = blockIdx.x;
  const int b0 = bix0 >> 5;
  const int q0 = (bix0 & 31) * PXB;
  const float* xt0 = x + (size_t)b0 * (DD * HW) + q0;
  const int bix1 = blockIdx.x + NBLK;
  const int b1 = bix1 >> 5;
  const int q1 = (bix1 & 31) * PXB;
  const float* xt1 = x + (size_t)b1 * (DD * HW) + q1;

  // ---- stage prebuilt codebook ONCE (serves both tiles) ----
  #pragma unroll
  for (int s = 0; s < 8; ++s) wlds[tid + s * NTH] = wswz[tid + s * NTH];
  w2s[tid] = w2g[tid];   // KC == NTH
  __syncthreads();       // the ONLY block barrier

  const short8* wl8 = (const short8*)wlds;

  wave_tile(xt0, w, w2s, wl8, candm, Xs, sidx,
            out_q + (size_t)b0 * (DD * HW) + q0,
            out_enc + (size_t)bix0 * (PXB * KC) + wv * 8192,
            out_idx, partial, bix0, lane, wv);
  wave_tile(xt1, w, w2s, wl8, candm, Xs, sidx,
            out_q + (size_t)b1 * (DD * HW) + q1,
            out_enc + (size_t)bix1 * (PXB * KC) + wv * 8192,
            out_idx, partial, bix1, lane, wv);
}

// --- epilogue: loss = vq + commit = 2 * mean((q - x)^2) ---
__global__ void finish_kernel(const double* __restrict__ partial,
                              float* __restrict__ out) {
  int t = threadIdx.x;   // 256 threads, 8192 per-wave partials
  double s = 0.0;
  #pragma unroll
  for (int i = 0; i < 32; ++i) s += partial[t + 256 * i];
  #pragma unroll
  for (int off = 32; off > 0; off >>= 1) s += __shfl_down(s, off);
  __shared__ double sr[4];
  if ((t & 63) == 0) sr[t >> 6] = s;
  __syncthreads();
  if (t == 0)
    out[0] = (float)(2.0 * (sr[0] + sr[1] + sr[2] + sr[3]) / (double)QSIZE);
}

extern "C" void kernel_launch(void* const* d_in, const int* in_sizes, int n_in,
                              void* d_out, int out_size, void* d_ws, size_t ws_size,
                              hipStream_t stream) {
  const float* x = (const float*)d_in[0];   // [32,64,64,64] f32 NCHW
  const float* w = (const float*)d_in[1];   // [512,64] f32
  float* out = (float*)d_out;
  float* out_q = out + 1;
  float* out_enc = out_q + QSIZE;
  float* out_idx = out_enc + (size_t)NPIX * KC;

  // d_ws layout: partial[8192] @0 (64 KB) | w2g[512] @65536 | wswz[4096] @69632
  double* partial = (double*)d_ws;
  float* w2g = (float*)((char*)d_ws + 65536);
  uint4* wswz = (uint4*)((char*)d_ws + 69632);

  prep<<<4, 1024, 0, stream>>>(w, w2g, wswz);
  vq_fused<<<NBLK, NTH, 0, stream>>>(x, w, w2g, wswz, out_q, out_enc, out_idx, partial);
  finish_kernel<<<1, 256, 0, stream>>>(partial, out);
}

// Round 9
// 373.830 us; speedup vs baseline: 1.3233x; 1.0800x over previous
//
#include <hip/hip_runtime.h>
#include <cfloat>

#define KC 512        // codes
#define DD 64         // dim
#define HW 4096       // 64*64
#define NPIX 131072   // 32*64*64
#define QSIZE 8388608 // 32*64*64*64
#define PXB 128       // pixels per tile
#define NTILE (NPIX / PXB)   // 1024 tiles
#define NBLK (NTILE / 2)     // 512 persistent blocks, 2 tiles each
#define NTH 512       // 8 waves
#define MARGIN 4.0e-3f  // >6x worst-case screen-vs-np error bound

typedef short short8 __attribute__((ext_vector_type(8)));   // 8 bf16 MFMA operand
typedef float f32x4 __attribute__((ext_vector_type(4)));
typedef float nfloat4 __attribute__((ext_vector_type(4)));
typedef unsigned long long u64;

__device__ __forceinline__ unsigned short bf16_rne(float f) {
    unsigned int u = __float_as_uint(f);
    u += 0x7FFFu + ((u >> 16) & 1u);
    return (unsigned short)(u >> 16);
}

// LDS-only barrier: syncs waves + orders DS ops without draining vmcnt —
// in-flight NT output stores keep streaming across it. Legal: no global RAW
// crosses these barriers (the mode1 zeros->ones ordering goes through the one
// full __syncthreads instead).
__device__ __forceinline__ void barrier_lds_only() {
    asm volatile("s_waitcnt lgkmcnt(0)" ::: "memory");
    __builtin_amdgcn_s_barrier();
    __builtin_amdgcn_sched_barrier(0);
}

// --- prep (once per launch, validated R10): swizzled bf16 B-frag codebook
// (64 KB) + np-pairwise w2. Slot s=(ct*2+kc)*64+ln holds
// w[ct*16+(ln&15)][kc*32+(ln>>4)*8 .. +8) as bf16x8.
__global__ __launch_bounds__(1024) void prep(
    const float* __restrict__ w, float* __restrict__ w2g,
    uint4* __restrict__ wswz) {
  const int gt = blockIdx.x * 1024 + threadIdx.x;   // 0..4095
  {
    int ct = gt >> 7, kc = (gt >> 6) & 1, ln = gt & 63;
    int n = ln & 15, q = ln >> 4;
    const float* wp = w + (ct * 16 + n) * DD + kc * 32 + q * 8;
    nfloat4 f0 = *(const nfloat4*)(wp);
    nfloat4 f1 = *(const nfloat4*)(wp + 4);
    uint4 u;
    u.x = (unsigned)bf16_rne(f0[0]) | ((unsigned)bf16_rne(f0[1]) << 16);
    u.y = (unsigned)bf16_rne(f0[2]) | ((unsigned)bf16_rne(f0[3]) << 16);
    u.z = (unsigned)bf16_rne(f1[0]) | ((unsigned)bf16_rne(f1[1]) << 16);
    u.w = (unsigned)bf16_rne(f1[2]) | ((unsigned)bf16_rne(f1[3]) << 16);
    wswz[gt] = u;
  }
  if (gt < KC) {      // w2g[k]: numpy-pairwise fp32 sum of squares
    const float* wk = w + gt * DD;
    float r0 = __fmul_rn(wk[0], wk[0]), r1 = __fmul_rn(wk[1], wk[1]),
          r2 = __fmul_rn(wk[2], wk[2]), r3 = __fmul_rn(wk[3], wk[3]),
          r4 = __fmul_rn(wk[4], wk[4]), r5 = __fmul_rn(wk[5], wk[5]),
          r6 = __fmul_rn(wk[6], wk[6]), r7 = __fmul_rn(wk[7], wk[7]);
    #pragma unroll
    for (int i = 8; i < DD; i += 8) {
      r0 = __fadd_rn(r0, __fmul_rn(wk[i+0], wk[i+0]));
      r1 = __fadd_rn(r1, __fmul_rn(wk[i+1], wk[i+1]));
      r2 = __fadd_rn(r2, __fmul_rn(wk[i+2], wk[i+2]));
      r3 = __fadd_rn(r3, __fmul_rn(wk[i+3], wk[i+3]));
      r4 = __fadd_rn(r4, __fmul_rn(wk[i+4], wk[i+4]));
      r5 = __fadd_rn(r5, __fmul_rn(wk[i+5], wk[i+5]));
      r6 = __fadd_rn(r6, __fmul_rn(wk[i+6], wk[i+6]));
      r7 = __fadd_rn(r7, __fmul_rn(wk[i+7], wk[i+7]));
    }
    w2g[gt] = __fadd_rn(__fadd_rn(__fadd_rn(r0, r1), __fadd_rn(r2, r3)),
                        __fadd_rn(__fadd_rn(r4, r5), __fadd_rn(r6, r7)));
  }
}

// ======== per-tile phase helpers (bodies identical to R0/R4's 381 µs kernel) ====

__device__ __forceinline__ void tile_prelude(
    const float* __restrict__ xt, float* Xs, u64 (*candm)[8],
    short8& a0, short8& a1, int tid, int lane, int wv) {
  ((u64*)candm)[tid] = 0;
  ((u64*)candm)[tid + NTH] = 0;
  if (tid < PXB) {
    const float* xp = xt + tid;
    float r0 = __fmul_rn(xp[0*HW], xp[0*HW]), r1 = __fmul_rn(xp[1*HW], xp[1*HW]),
          r2 = __fmul_rn(xp[2*HW], xp[2*HW]), r3 = __fmul_rn(xp[3*HW], xp[3*HW]),
          r4 = __fmul_rn(xp[4*HW], xp[4*HW]), r5 = __fmul_rn(xp[5*HW], xp[5*HW]),
          r6 = __fmul_rn(xp[6*HW], xp[6*HW]), r7 = __fmul_rn(xp[7*HW], xp[7*HW]);
    #pragma unroll
    for (int i = 8; i < DD; i += 8) {
      r0 = __fadd_rn(r0, __fmul_rn(xp[(size_t)(i+0)*HW], xp[(size_t)(i+0)*HW]));
      r1 = __fadd_rn(r1, __fmul_rn(xp[(size_t)(i+1)*HW], xp[(size_t)(i+1)*HW]));
      r2 = __fadd_rn(r2, __fmul_rn(xp[(size_t)(i+2)*HW], xp[(size_t)(i+2)*HW]));
      r3 = __fadd_rn(r3, __fmul_rn(xp[(size_t)(i+3)*HW], xp[(size_t)(i+3)*HW]));
      r4 = __fadd_rn(r4, __fmul_rn(xp[(size_t)(i+4)*HW], xp[(size_t)(i+4)*HW]));
      r5 = __fadd_rn(r5, __fmul_rn(xp[(size_t)(i+5)*HW], xp[(size_t)(i+5)*HW]));
      r6 = __fadd_rn(r6, __fmul_rn(xp[(size_t)(i+6)*HW], xp[(size_t)(i+6)*HW]));
      r7 = __fadd_rn(r7, __fmul_rn(xp[(size_t)(i+7)*HW], xp[(size_t)(i+7)*HW]));
    }
    Xs[tid] = __fadd_rn(__fadd_rn(__fadd_rn(r0, r1), __fadd_rn(r2, r3)),
                        __fadd_rn(__fadd_rn(r4, r5), __fadd_rn(r6, r7)));
  }
  const int am = lane & 15, aq = lane >> 4;
  const float* xa = xt + wv * 16 + am;
  #pragma unroll
  for (int j = 0; j < 8; ++j) {
    a0[j] = (short)bf16_rne(-2.0f * xa[(size_t)(aq * 8 + j) * HW]);
    a1[j] = (short)bf16_rne(-2.0f * xa[(size_t)(32 + aq * 8 + j) * HW]);
  }
}

__device__ __forceinline__ void tile_screen(
    const short8* wl8, const float* w2s, u64 (*candm)[8],
    short8 a0, short8 a1, int lane, int wv) {
  const int cn = lane & 15;
  // pass 1: per-pixel min of screened S over 512 codes
  // C layout (m89-verified): col=lane&15, row=(lane>>4)*4+reg
  float m0 = FLT_MAX, m1 = FLT_MAX, m2 = FLT_MAX, m3 = FLT_MAX;
  for (int ct = 0; ct < 32; ++ct) {
    float wk2 = w2s[ct * 16 + cn];
    f32x4 acc = {wk2, wk2, wk2, wk2};
    acc = __builtin_amdgcn_mfma_f32_16x16x32_bf16(a0, wl8[ct * 128 + lane], acc, 0, 0, 0);
    acc = __builtin_amdgcn_mfma_f32_16x16x32_bf16(a1, wl8[ct * 128 + 64 + lane], acc, 0, 0, 0);
    m0 = fminf(m0, acc[0]); m1 = fminf(m1, acc[1]);
    m2 = fminf(m2, acc[2]); m3 = fminf(m3, acc[3]);
  }
  #pragma unroll
  for (int s = 1; s < 16; s <<= 1) {
    m0 = fminf(m0, __shfl_xor(m0, s));
    m1 = fminf(m1, __shfl_xor(m1, s));
    m2 = fminf(m2, __shfl_xor(m2, s));
    m3 = fminf(m3, __shfl_xor(m3, s));
  }
  const float t0 = m0 + MARGIN, t1 = m1 + MARGIN,
              t2 = m2 + MARGIN, t3 = m3 + MARGIN;
  // pass 2: flag candidates into per-pixel bitmasks
  for (int ct = 0; ct < 32; ++ct) {
    float wk2 = w2s[ct * 16 + cn];
    f32x4 acc = {wk2, wk2, wk2, wk2};
    acc = __builtin_amdgcn_mfma_f32_16x16x32_bf16(a0, wl8[ct * 128 + lane], acc, 0, 0, 0);
    acc = __builtin_amdgcn_mfma_f32_16x16x32_bf16(a1, wl8[ct * 128 + 64 + lane], acc, 0, 0, 0);
    u64 bm0 = __ballot(acc[0] <= t0);
    u64 bm1 = __ballot(acc[1] <= t1);
    u64 bm2 = __ballot(acc[2] <= t2);
    u64 bm3 = __ballot(acc[3] <= t3);
    if (lane < 4) {   // lane r owns reg r; ballot bit (q*16+n) -> pixel q*4+r, code ct*16+n
      u64 mk = (lane == 0) ? bm0 : (lane == 1) ? bm1 : (lane == 2) ? bm2 : bm3;
      int word = ct >> 2, sh = (ct & 3) * 16;
      #pragma unroll
      for (int q = 0; q < 4; ++q) {
        u64 bits = (mk >> (q * 16)) & 0xFFFFull;
        if (bits) candm[wv * 16 + q * 4 + lane][word] |= bits << sh;
      }
    }
  }
}

__device__ __forceinline__ void tile_refine(
    const float* __restrict__ xt, const float* __restrict__ w,
    const float* w2s, const float* Xs, const u64 (*candm)[8],
    int* sidx, float* __restrict__ out_idx, int bix, int tid, int lane) {
  const int px = tid >> 2, part = tid & 3;
  const float X = Xs[px];
  const float* xr = xt + px;
  float bestd = FLT_MAX; int bk = 1 << 30;
  for (int wd = part * 2; wd < part * 2 + 2; ++wd) {
    u64 msk = candm[px][wd];
    while (msk) {
      int bit = __ffsll((unsigned long long)msk) - 1;
      msk &= msk - 1;
      int k = wd * 64 + bit;
      const float* wp = w + k * DD;
      float P = 0.f;                       // ascending-d fma chain (BLAS order)
      #pragma unroll
      for (int dc = 0; dc < 16; ++dc) {
        nfloat4 w4 = *(const nfloat4*)(wp + dc * 4);
        P = __fmaf_rn(xr[(size_t)(dc * 4 + 0) * HW], w4[0], P);
        P = __fmaf_rn(xr[(size_t)(dc * 4 + 1) * HW], w4[1], P);
        P = __fmaf_rn(xr[(size_t)(dc * 4 + 2) * HW], w4[2], P);
        P = __fmaf_rn(xr[(size_t)(dc * 4 + 3) * HW], w4[3], P);
      }
      float dist = __fsub_rn(__fadd_rn(X, w2s[k]), __fadd_rn(P, P));
      if (dist < bestd || (dist == bestd && k < bk)) { bestd = dist; bk = k; }
    }
  }
  float od = __shfl_down(bestd, 1); int ok = __shfl_down(bk, 1);
  if ((lane & 3) < 3 && (od < bestd || (od == bestd && ok < bk))) { bestd = od; bk = ok; }
  od = __shfl_down(bestd, 2); ok = __shfl_down(bk, 2);
  if ((lane & 3) < 2 && (od < bestd || (od == bestd && ok < bk))) { bestd = od; bk = ok; }
  if (part == 0) {
    sidx[px] = bk;
    out_idx[bix * PXB + px] = (float)bk;
  }
}

__device__ __forceinline__ float tile_quant(
    const float* __restrict__ xt, const float* __restrict__ w,
    const int* sidx, float* __restrict__ qb, int tid) {
  float lsum = 0.f;
  for (int i = tid; i < PXB * DD; i += NTH) {   // 16 iters
    int d = i >> 7, pp = i & 127;
    float qv = w[sidx[pp] * DD + d];      // L1/L2-resident gather
    float dv = qv - xt[(size_t)d * HW + pp];
    lsum = __fmaf_rn(dv, dv, lsum);
    __builtin_nontemporal_store(qv, qb + (size_t)d * HW + pp);
  }
  return lsum;
}

__device__ __forceinline__ void tile_enc(
    const int* sidx, float* __restrict__ basep, int tid) {
  // fused one-hot enc (base ≡ 1 mod 4 floats: 3-head, aligned body, 1-tail)
  for (int t = tid; t < 16383; t += NTH) {
    int u = 3 + 4 * t;
    nfloat4 v;
    #pragma unroll
    for (int j = 0; j < 4; ++j) {
      int e = u + j;
      v[j] = (sidx[e >> 9] == (e & 511)) ? 1.0f : 0.0f;
    }
    __builtin_nontemporal_store(v, (nfloat4*)(basep + u));
  }
  if (tid < 3) basep[tid] = (sidx[0] == tid) ? 1.0f : 0.0f;
  else if (tid == 3) basep[PXB * KC - 1] = (sidx[127] == 511) ? 1.0f : 0.0f;
}

__device__ __forceinline__ void enc_zero_fill(float* __restrict__ basep, int tid) {
  // zero the 65536-float enc region (base ≡ 1 mod 4: 3-head, body, 1-tail)
  const nfloat4 z = {0.f, 0.f, 0.f, 0.f};
  if (tid < 3) __builtin_nontemporal_store(0.0f, basep + tid);
  else if (tid == 3) __builtin_nontemporal_store(0.0f, basep + PXB * KC - 1);
  for (int t = tid; t < 16383; t += NTH)
    __builtin_nontemporal_store(z, (nfloat4*)(basep + 3 + 4 * t));
}

// --- main R19: R4's persistent 2-tile structure (best, 381 µs) + checkerboard
// phase scheduling. Dispatch model: block i -> XCD i%8, sequential per XCD ->
// co-resident CU pair = {i, i+256}. mode0 (bix<256 or 512-767... (bix>>8)&1==0)
// = exactly R4. mode1 pre-fills BOTH tiles' enc regions with zeros up front
// (drained at the one full __syncthreads), then runs the identical argmin
// pipeline emitting only 128-point one-scatters + quant at the tails. On a
// mixed-pair CU, mode1's front write burst drains under mode0's compute and
// mode0's tail bursts drain under mode1's compute. Outputs byte-identical.
__global__ __launch_bounds__(NTH, 4) void vq_fused(
    const float* __restrict__ x, const float* __restrict__ w,
    const float* __restrict__ w2g, const uint4* __restrict__ wswz,
    float* __restrict__ out_q, float* __restrict__ out_enc,
    float* __restrict__ out_idx, double* __restrict__ partial) {

  __shared__ uint4 wlds[4096];        // 64 KB: B-frags, slot=(ct*2+kc)*64+lane
  __shared__ float w2s[KC];           // 2 KB: np-exact ||w_k||^2
  __shared__ u64 candm[PXB][8];       // 8 KB: 512-bit candidate mask per pixel
  __shared__ float Xs[PXB];           // np-exact ||x||^2 per pixel
  __shared__ int sidx[PXB];
  __shared__ float sredf[8];

  const int tid = threadIdx.x;
  const int lane = tid & 63;
  const int wv = tid >> 6;            // wave 0..7, each owns 16 pixels
  const int mode = (blockIdx.x >> 8) & 1;   // co-resident pair {i, i+256} mixed

  // tile A = blockIdx.x, tile B = blockIdx.x + 512
  const int bix0 = blockIdx.x;
  const int b0 = bix0 >> 5;
  const int q0 = (bix0 & 31) * PXB;
  const float* xt0 = x + (size_t)b0 * (DD * HW) + q0;
  const int bix1 = blockIdx.x + NBLK;
  const int b1 = bix1 >> 5;
  const int q1 = (bix1 & 31) * PXB;
  const float* xt1 = x + (size_t)b1 * (DD * HW) + q1;
  float* bp0 = out_enc + (size_t)bix0 * (PXB * KC);
  float* bp1 = out_enc + (size_t)bix1 * (PXB * KC);

  // ---- stage prebuilt codebook ONCE (serves both tiles) ----
  #pragma unroll
  for (int s = 0; s < 8; ++s) wlds[tid + s * NTH] = wswz[tid + s * NTH];
  w2s[tid] = w2g[tid];   // KC == NTH

  short8 a0, a1;
  tile_prelude(xt0, Xs, candm, a0, a1, tid, lane, wv);
  if (mode) {            // mode1: front-load both tiles' enc zeros
    enc_zero_fill(bp0, tid);
    enc_zero_fill(bp1, tid);
  }
  __syncthreads();       // codebook/candm/Xs ready; mode1: zeros DRAINED
                         // (vmcnt(0) in syncthreads orders zeros before ones)

  const short8* wl8 = (const short8*)wlds;

  // ================= TILE A =================
  tile_screen(wl8, w2s, candm, a0, a1, lane, wv);
  barrier_lds_only();    // candm-A ready
  tile_refine(xt0, w, w2s, Xs, candm, sidx, out_idx, bix0, tid, lane);
  barrier_lds_only();    // sidx-A ready; all waves past refine-A

  // prelude-B FIRST (loads issue before the A-output store burst; overwrites
  // Xs/candm — safe, refine-A done; sidx untouched), then A outputs.
  tile_prelude(xt1, Xs, candm, a0, a1, tid, lane, wv);
  if (mode) {            // ones-scatter over pre-drained zeros
    if (tid < PXB)
      __builtin_nontemporal_store(1.0f, bp0 + tid * KC + sidx[tid]);
  }
  {
    float lsum = tile_quant(xt0, w, sidx, out_q + (size_t)b0 * (DD * HW) + q0, tid);
    #pragma unroll
    for (int off = 32; off > 0; off >>= 1) lsum += __shfl_down(lsum, off);
    if (lane == 0) sredf[wv] = lsum;
  }
  if (!mode) tile_enc(sidx, bp0, tid);
  barrier_lds_only();    // sredf/Xs-B/candm-B ready; A stores stay in flight
  if (tid == 0) {
    double t = 0.0;
    #pragma unroll
    for (int i = 0; i < 8; ++i) t += (double)sredf[i];
    partial[bix0] = t;
  }

  // ================= TILE B =================
  tile_screen(wl8, w2s, candm, a0, a1, lane, wv);   // zero VMEM: A stores drain here
  barrier_lds_only();    // candm-B ready
  tile_refine(xt1, w, w2s, Xs, candm, sidx, out_idx, bix1, tid, lane);
  barrier_lds_only();    // sidx-B ready
  if (mode) {
    if (tid < PXB)
      __builtin_nontemporal_store(1.0f, bp1 + tid * KC + sidx[tid]);
  }
  {
    float lsum = tile_quant(xt1, w, sidx, out_q + (size_t)b1 * (DD * HW) + q1, tid);
    #pragma unroll
    for (int off = 32; off > 0; off >>= 1) lsum += __shfl_down(lsum, off);
    if (lane == 0) sredf[wv] = lsum;
  }
  if (!mode) tile_enc(sidx, bp1, tid);
  barrier_lds_only();    // sredf-B ready
  if (tid == 0) {
    double t = 0.0;
    #pragma unroll
    for (int i = 0; i < 8; ++i) t += (double)sredf[i];
    partial[bix1] = t;
  }
  // kernel end: implicit full drain of tile-B stores
}

// --- epilogue: loss = vq + commit = 2 * mean((q - x)^2) ---
__global__ void finish_kernel(const double* __restrict__ partial,
                              float* __restrict__ out) {
  int t = threadIdx.x;   // 256 threads, 1024 partials
  double s = partial[t] + partial[t + 256] + partial[t + 512] + partial[t + 768];
  #pragma unroll
  for (int off = 32; off > 0; off >>= 1) s += __shfl_down(s, off);
  __shared__ double sr[4];
  if ((t & 63) == 0) sr[t >> 6] = s;
  __syncthreads();
  if (t == 0)
    out[0] = (float)(2.0 * (sr[0] + sr[1] + sr[2] + sr[3]) / (double)QSIZE);
}

extern "C" void kernel_launch(void* const* d_in, const int* in_sizes, int n_in,
                              void* d_out, int out_size, void* d_ws, size_t ws_size,
                              hipStream_t stream) {
  const float* x = (const float*)d_in[0];   // [32,64,64,64] f32 NCHW
  const float* w = (const float*)d_in[1];   // [512,64] f32
  float* out = (float*)d_out;
  float* out_q = out + 1;
  float* out_enc = out_q + QSIZE;
  float* out_idx = out_enc + (size_t)NPIX * KC;

  // d_ws layout: partial[1024] @0 (8 KB) | w2g[512] @8192 | wswz[4096] @16384
  double* partial = (double*)d_ws;
  float* w2g = (float*)((char*)d_ws + 8192);
  uint4* wswz = (uint4*)((char*)d_ws + 16384);

  prep<<<4, 1024, 0, stream>>>(w, w2g, wswz);
  vq_fused<<<NBLK, NTH, 0, stream>>>(x, w, w2g, wswz, out_q, out_enc, out_idx, partial);
  finish_kernel<<<1, 256, 0, stream>>>(partial, out);
}

// Round 10
// 372.531 us; speedup vs baseline: 1.3279x; 1.0035x over previous
//
#include <hip/hip_runtime.h>
#include <cfloat>

#define KC 512        // codes
#define DD 64         // dim
#define HW 4096       // 64*64
#define NPIX 131072   // 32*64*64
#define QSIZE 8388608 // 32*64*64*64
#define PXB 128       // pixels per tile
#define NTILE (NPIX / PXB)   // 1024 tiles
#define NBLK (NTILE / 2)     // 512 persistent blocks, 2 tiles each
#define NTH 512       // 8 waves
#define MARGIN 4.0e-3f  // >6x worst-case screen-vs-np error bound

typedef short short8 __attribute__((ext_vector_type(8)));   // 8 bf16 MFMA operand
typedef float f32x4 __attribute__((ext_vector_type(4)));
typedef float nfloat4 __attribute__((ext_vector_type(4)));
typedef unsigned long long u64;

__device__ __forceinline__ unsigned short bf16_rne(float f) {
    unsigned int u = __float_as_uint(f);
    u += 0x7FFFu + ((u >> 16) & 1u);
    return (unsigned short)(u >> 16);
}

// LDS-only barrier: syncs waves + orders DS ops without draining vmcnt —
// in-flight NT output stores keep streaming across it.
__device__ __forceinline__ void barrier_lds_only() {
    asm volatile("s_waitcnt lgkmcnt(0)" ::: "memory");
    __builtin_amdgcn_s_barrier();
    __builtin_amdgcn_sched_barrier(0);
}

// Full-drain barrier: all VMEM (incl. NT stores) + DS retired, then barrier.
// Used by mode1 ONCE, post-refine-A, to order enc zeros before ones-scatters.
__device__ __forceinline__ void barrier_full_drain() {
    asm volatile("s_waitcnt vmcnt(0) lgkmcnt(0)" ::: "memory");
    __builtin_amdgcn_s_barrier();
    __builtin_amdgcn_sched_barrier(0);
}

// --- prep (once per launch, validated R10): swizzled bf16 B-frag codebook
// (64 KB) + np-pairwise w2. Slot s=(ct*2+kc)*64+ln holds
// w[ct*16+(ln&15)][kc*32+(ln>>4)*8 .. +8) as bf16x8.
__global__ __launch_bounds__(1024) void prep(
    const float* __restrict__ w, float* __restrict__ w2g,
    uint4* __restrict__ wswz) {
  const int gt = blockIdx.x * 1024 + threadIdx.x;   // 0..4095
  {
    int ct = gt >> 7, kc = (gt >> 6) & 1, ln = gt & 63;
    int n = ln & 15, q = ln >> 4;
    const float* wp = w + (ct * 16 + n) * DD + kc * 32 + q * 8;
    nfloat4 f0 = *(const nfloat4*)(wp);
    nfloat4 f1 = *(const nfloat4*)(wp + 4);
    uint4 u;
    u.x = (unsigned)bf16_rne(f0[0]) | ((unsigned)bf16_rne(f0[1]) << 16);
    u.y = (unsigned)bf16_rne(f0[2]) | ((unsigned)bf16_rne(f0[3]) << 16);
    u.z = (unsigned)bf16_rne(f1[0]) | ((unsigned)bf16_rne(f1[1]) << 16);
    u.w = (unsigned)bf16_rne(f1[2]) | ((unsigned)bf16_rne(f1[3]) << 16);
    wswz[gt] = u;
  }
  if (gt < KC) {      // w2g[k]: numpy-pairwise fp32 sum of squares
    const float* wk = w + gt * DD;
    float r0 = __fmul_rn(wk[0], wk[0]), r1 = __fmul_rn(wk[1], wk[1]),
          r2 = __fmul_rn(wk[2], wk[2]), r3 = __fmul_rn(wk[3], wk[3]),
          r4 = __fmul_rn(wk[4], wk[4]), r5 = __fmul_rn(wk[5], wk[5]),
          r6 = __fmul_rn(wk[6], wk[6]), r7 = __fmul_rn(wk[7], wk[7]);
    #pragma unroll
    for (int i = 8; i < DD; i += 8) {
      r0 = __fadd_rn(r0, __fmul_rn(wk[i+0], wk[i+0]));
      r1 = __fadd_rn(r1, __fmul_rn(wk[i+1], wk[i+1]));
      r2 = __fadd_rn(r2, __fmul_rn(wk[i+2], wk[i+2]));
      r3 = __fadd_rn(r3, __fmul_rn(wk[i+3], wk[i+3]));
      r4 = __fadd_rn(r4, __fmul_rn(wk[i+4], wk[i+4]));
      r5 = __fadd_rn(r5, __fmul_rn(wk[i+5], wk[i+5]));
      r6 = __fadd_rn(r6, __fmul_rn(wk[i+6], wk[i+6]));
      r7 = __fadd_rn(r7, __fmul_rn(wk[i+7], wk[i+7]));
    }
    w2g[gt] = __fadd_rn(__fadd_rn(__fadd_rn(r0, r1), __fadd_rn(r2, r3)),
                        __fadd_rn(__fadd_rn(r4, r5), __fadd_rn(r6, r7)));
  }
}

// ======== per-tile phase helpers (bodies identical to R0/R4's kernel) ====

__device__ __forceinline__ void tile_prelude(
    const float* __restrict__ xt, float* Xs, u64 (*candm)[8],
    short8& a0, short8& a1, int tid, int lane, int wv) {
  ((u64*)candm)[tid] = 0;
  ((u64*)candm)[tid + NTH] = 0;
  if (tid < PXB) {
    const float* xp = xt + tid;
    float r0 = __fmul_rn(xp[0*HW], xp[0*HW]), r1 = __fmul_rn(xp[1*HW], xp[1*HW]),
          r2 = __fmul_rn(xp[2*HW], xp[2*HW]), r3 = __fmul_rn(xp[3*HW], xp[3*HW]),
          r4 = __fmul_rn(xp[4*HW], xp[4*HW]), r5 = __fmul_rn(xp[5*HW], xp[5*HW]),
          r6 = __fmul_rn(xp[6*HW], xp[6*HW]), r7 = __fmul_rn(xp[7*HW], xp[7*HW]);
    #pragma unroll
    for (int i = 8; i < DD; i += 8) {
      r0 = __fadd_rn(r0, __fmul_rn(xp[(size_t)(i+0)*HW], xp[(size_t)(i+0)*HW]));
      r1 = __fadd_rn(r1, __fmul_rn(xp[(size_t)(i+1)*HW], xp[(size_t)(i+1)*HW]));
      r2 = __fadd_rn(r2, __fmul_rn(xp[(size_t)(i+2)*HW], xp[(size_t)(i+2)*HW]));
      r3 = __fadd_rn(r3, __fmul_rn(xp[(size_t)(i+3)*HW], xp[(size_t)(i+3)*HW]));
      r4 = __fadd_rn(r4, __fmul_rn(xp[(size_t)(i+4)*HW], xp[(size_t)(i+4)*HW]));
      r5 = __fadd_rn(r5, __fmul_rn(xp[(size_t)(i+5)*HW], xp[(size_t)(i+5)*HW]));
      r6 = __fadd_rn(r6, __fmul_rn(xp[(size_t)(i+6)*HW], xp[(size_t)(i+6)*HW]));
      r7 = __fadd_rn(r7, __fmul_rn(xp[(size_t)(i+7)*HW], xp[(size_t)(i+7)*HW]));
    }
    Xs[tid] = __fadd_rn(__fadd_rn(__fadd_rn(r0, r1), __fadd_rn(r2, r3)),
                        __fadd_rn(__fadd_rn(r4, r5), __fadd_rn(r6, r7)));
  }
  const int am = lane & 15, aq = lane >> 4;
  const float* xa = xt + wv * 16 + am;
  #pragma unroll
  for (int j = 0; j < 8; ++j) {
    a0[j] = (short)bf16_rne(-2.0f * xa[(size_t)(aq * 8 + j) * HW]);
    a1[j] = (short)bf16_rne(-2.0f * xa[(size_t)(32 + aq * 8 + j) * HW]);
  }
}

__device__ __forceinline__ void tile_screen(
    const short8* wl8, const float* w2s, u64 (*candm)[8],
    short8 a0, short8 a1, int lane, int wv) {
  const int cn = lane & 15;
  // pass 1: per-pixel min of screened S over 512 codes
  // C layout (m89-verified): col=lane&15, row=(lane>>4)*4+reg
  float m0 = FLT_MAX, m1 = FLT_MAX, m2 = FLT_MAX, m3 = FLT_MAX;
  for (int ct = 0; ct < 32; ++ct) {
    float wk2 = w2s[ct * 16 + cn];
    f32x4 acc = {wk2, wk2, wk2, wk2};
    acc = __builtin_amdgcn_mfma_f32_16x16x32_bf16(a0, wl8[ct * 128 + lane], acc, 0, 0, 0);
    acc = __builtin_amdgcn_mfma_f32_16x16x32_bf16(a1, wl8[ct * 128 + 64 + lane], acc, 0, 0, 0);
    m0 = fminf(m0, acc[0]); m1 = fminf(m1, acc[1]);
    m2 = fminf(m2, acc[2]); m3 = fminf(m3, acc[3]);
  }
  #pragma unroll
  for (int s = 1; s < 16; s <<= 1) {
    m0 = fminf(m0, __shfl_xor(m0, s));
    m1 = fminf(m1, __shfl_xor(m1, s));
    m2 = fminf(m2, __shfl_xor(m2, s));
    m3 = fminf(m3, __shfl_xor(m3, s));
  }
  const float t0 = m0 + MARGIN, t1 = m1 + MARGIN,
              t2 = m2 + MARGIN, t3 = m3 + MARGIN;
  // pass 2: flag candidates into per-pixel bitmasks
  for (int ct = 0; ct < 32; ++ct) {
    float wk2 = w2s[ct * 16 + cn];
    f32x4 acc = {wk2, wk2, wk2, wk2};
    acc = __builtin_amdgcn_mfma_f32_16x16x32_bf16(a0, wl8[ct * 128 + lane], acc, 0, 0, 0);
    acc = __builtin_amdgcn_mfma_f32_16x16x32_bf16(a1, wl8[ct * 128 + 64 + lane], acc, 0, 0, 0);
    u64 bm0 = __ballot(acc[0] <= t0);
    u64 bm1 = __ballot(acc[1] <= t1);
    u64 bm2 = __ballot(acc[2] <= t2);
    u64 bm3 = __ballot(acc[3] <= t3);
    if (lane < 4) {   // lane r owns reg r; ballot bit (q*16+n) -> pixel q*4+r, code ct*16+n
      u64 mk = (lane == 0) ? bm0 : (lane == 1) ? bm1 : (lane == 2) ? bm2 : bm3;
      int word = ct >> 2, sh = (ct & 3) * 16;
      #pragma unroll
      for (int q = 0; q < 4; ++q) {
        u64 bits = (mk >> (q * 16)) & 0xFFFFull;
        if (bits) candm[wv * 16 + q * 4 + lane][word] |= bits << sh;
      }
    }
  }
}

__device__ __forceinline__ void tile_refine(
    const float* __restrict__ xt, const float* __restrict__ w,
    const float* w2s, const float* Xs, const u64 (*candm)[8],
    int* sidx, float* __restrict__ out_idx, int bix, int tid, int lane) {
  const int px = tid >> 2, part = tid & 3;
  const float X = Xs[px];
  const float* xr = xt + px;
  float bestd = FLT_MAX; int bk = 1 << 30;
  for (int wd = part * 2; wd < part * 2 + 2; ++wd) {
    u64 msk = candm[px][wd];
    while (msk) {
      int bit = __ffsll((unsigned long long)msk) - 1;
      msk &= msk - 1;
      int k = wd * 64 + bit;
      const float* wp = w + k * DD;
      float P = 0.f;                       // ascending-d fma chain (BLAS order)
      #pragma unroll
      for (int dc = 0; dc < 16; ++dc) {
        nfloat4 w4 = *(const nfloat4*)(wp + dc * 4);
        P = __fmaf_rn(xr[(size_t)(dc * 4 + 0) * HW], w4[0], P);
        P = __fmaf_rn(xr[(size_t)(dc * 4 + 1) * HW], w4[1], P);
        P = __fmaf_rn(xr[(size_t)(dc * 4 + 2) * HW], w4[2], P);
        P = __fmaf_rn(xr[(size_t)(dc * 4 + 3) * HW], w4[3], P);
      }
      float dist = __fsub_rn(__fadd_rn(X, w2s[k]), __fadd_rn(P, P));
      if (dist < bestd || (dist == bestd && k < bk)) { bestd = dist; bk = k; }
    }
  }
  float od = __shfl_down(bestd, 1); int ok = __shfl_down(bk, 1);
  if ((lane & 3) < 3 && (od < bestd || (od == bestd && ok < bk))) { bestd = od; bk = ok; }
  od = __shfl_down(bestd, 2); ok = __shfl_down(bk, 2);
  if ((lane & 3) < 2 && (od < bestd || (od == bestd && ok < bk))) { bestd = od; bk = ok; }
  if (part == 0) {
    sidx[px] = bk;
    out_idx[bix * PXB + px] = (float)bk;
  }
}

__device__ __forceinline__ float tile_quant(
    const float* __restrict__ xt, const float* __restrict__ w,
    const int* sidx, float* __restrict__ qb, int tid) {
  float lsum = 0.f;
  for (int i = tid; i < PXB * DD; i += NTH) {   // 16 iters
    int d = i >> 7, pp = i & 127;
    float qv = w[sidx[pp] * DD + d];      // L1/L2-resident gather
    float dv = qv - xt[(size_t)d * HW + pp];
    lsum = __fmaf_rn(dv, dv, lsum);
    __builtin_nontemporal_store(qv, qb + (size_t)d * HW + pp);
  }
  return lsum;
}

__device__ __forceinline__ void tile_enc(
    const int* sidx, float* __restrict__ basep, int tid) {
  // fused one-hot enc (base ≡ 1 mod 4 floats: 3-head, aligned body, 1-tail)
  for (int t = tid; t < 16383; t += NTH) {
    int u = 3 + 4 * t;
    nfloat4 v;
    #pragma unroll
    for (int j = 0; j < 4; ++j) {
      int e = u + j;
      v[j] = (sidx[e >> 9] == (e & 511)) ? 1.0f : 0.0f;
    }
    __builtin_nontemporal_store(v, (nfloat4*)(basep + u));
  }
  if (tid < 3) basep[tid] = (sidx[0] == tid) ? 1.0f : 0.0f;
  else if (tid == 3) basep[PXB * KC - 1] = (sidx[127] == 511) ? 1.0f : 0.0f;
}

__device__ __forceinline__ void enc_zero_fill(float* __restrict__ basep, int tid) {
  // zero the 65536-float enc region (base ≡ 1 mod 4: 3-head, body, 1-tail)
  const nfloat4 z = {0.f, 0.f, 0.f, 0.f};
  if (tid < 3) __builtin_nontemporal_store(0.0f, basep + tid);
  else if (tid == 3) __builtin_nontemporal_store(0.0f, basep + PXB * KC - 1);
  for (int t = tid; t < 16383; t += NTH)
    __builtin_nontemporal_store(z, (nfloat4*)(basep + 3 + 4 * t));
}

// --- main R20: R9's checkerboard (best, 373.8 µs) with mode1's zero-drain
// DEFERRED. R9 drained the 512 KB front zero-burst at the staging
// __syncthreads (vmcnt(0)) — mode1 blocks stalled ~20 µs before screen-A.
// Now: mode1 staging barrier is lds-only (zeros stay in flight, draining
// under screen-A+refine-A), and the one required zeros-before-ones ordering
// happens at a full-drain barrier post-refine-A, where the wait is ~0.
// mode0 path bit-identical to R9. Outputs byte-identical.
__global__ __launch_bounds__(NTH, 4) void vq_fused(
    const float* __restrict__ x, const float* __restrict__ w,
    const float* __restrict__ w2g, const uint4* __restrict__ wswz,
    float* __restrict__ out_q, float* __restrict__ out_enc,
    float* __restrict__ out_idx, double* __restrict__ partial) {

  __shared__ uint4 wlds[4096];        // 64 KB: B-frags, slot=(ct*2+kc)*64+lane
  __shared__ float w2s[KC];           // 2 KB: np-exact ||w_k||^2
  __shared__ u64 candm[PXB][8];       // 8 KB: 512-bit candidate mask per pixel
  __shared__ float Xs[PXB];           // np-exact ||x||^2 per pixel
  __shared__ int sidx[PXB];
  __shared__ float sredf[8];

  const int tid = threadIdx.x;
  const int lane = tid & 63;
  const int wv = tid >> 6;            // wave 0..7, each owns 16 pixels
  const int mode = (blockIdx.x >> 8) & 1;   // co-resident pair {i, i+256} mixed

  // tile A = blockIdx.x, tile B = blockIdx.x + 512
  const int bix0 = blockIdx.x;
  const int b0 = bix0 >> 5;
  const int q0 = (bix0 & 31) * PXB;
  const float* xt0 = x + (size_t)b0 * (DD * HW) + q0;
  const int bix1 = blockIdx.x + NBLK;
  const int b1 = bix1 >> 5;
  const int q1 = (bix1 & 31) * PXB;
  const float* xt1 = x + (size_t)b1 * (DD * HW) + q1;
  float* bp0 = out_enc + (size_t)bix0 * (PXB * KC);
  float* bp1 = out_enc + (size_t)bix1 * (PXB * KC);

  // ---- stage prebuilt codebook ONCE (serves both tiles) ----
  #pragma unroll
  for (int s = 0; s < 8; ++s) wlds[tid + s * NTH] = wswz[tid + s * NTH];
  w2s[tid] = w2g[tid];   // KC == NTH

  short8 a0, a1;
  tile_prelude(xt0, Xs, candm, a0, a1, tid, lane, wv);
  if (mode) {            // mode1: front-load both tiles' enc zeros (in flight)
    enc_zero_fill(bp0, tid);
    enc_zero_fill(bp1, tid);
    barrier_lds_only();  // staging needs DS-visibility only; zeros NOT drained
  } else {
    __syncthreads();     // mode0: identical to R9 (nothing outstanding anyway)
  }

  const short8* wl8 = (const short8*)wlds;

  // ================= TILE A =================
  tile_screen(wl8, w2s, candm, a0, a1, lane, wv);
  barrier_lds_only();    // candm-A ready
  tile_refine(xt0, w, w2s, Xs, candm, sidx, out_idx, bix0, tid, lane);
  if (mode) {
    barrier_full_drain(); // zeros (both tiles) retired — drained in background
                          // under screen-A+refine-A; wait here ~0. Orders
                          // zeros before BOTH ones-scatters.
  } else {
    barrier_lds_only();   // sidx-A ready
  }

  // prelude-B FIRST (loads issue before the A-output store burst; overwrites
  // Xs/candm — safe, refine-A done; sidx untouched), then A outputs.
  tile_prelude(xt1, Xs, candm, a0, a1, tid, lane, wv);
  if (mode) {            // ones-scatter over drained zeros
    if (tid < PXB)
      __builtin_nontemporal_store(1.0f, bp0 + tid * KC + sidx[tid]);
  }
  {
    float lsum = tile_quant(xt0, w, sidx, out_q + (size_t)b0 * (DD * HW) + q0, tid);
    #pragma unroll
    for (int off = 32; off > 0; off >>= 1) lsum += __shfl_down(lsum, off);
    if (lane == 0) sredf[wv] = lsum;
  }
  if (!mode) tile_enc(sidx, bp0, tid);
  barrier_lds_only();    // sredf/Xs-B/candm-B ready; A stores stay in flight
  if (tid == 0) {
    double t = 0.0;
    #pragma unroll
    for (int i = 0; i < 8; ++i) t += (double)sredf[i];
    partial[bix0] = t;
  }

  // ================= TILE B =================
  tile_screen(wl8, w2s, candm, a0, a1, lane, wv);   // zero VMEM: A stores drain here
  barrier_lds_only();    // candm-B ready
  tile_refine(xt1, w, w2s, Xs, candm, sidx, out_idx, bix1, tid, lane);
  barrier_lds_only();    // sidx-B ready
  if (mode) {            // zeros-B already ordered by the post-refine-A drain
    if (tid < PXB)
      __builtin_nontemporal_store(1.0f, bp1 + tid * KC + sidx[tid]);
  }
  {
    float lsum = tile_quant(xt1, w, sidx, out_q + (size_t)b1 * (DD * HW) + q1, tid);
    #pragma unroll
    for (int off = 32; off > 0; off >>= 1) lsum += __shfl_down(lsum, off);
    if (lane == 0) sredf[wv] = lsum;
  }
  if (!mode) tile_enc(sidx, bp1, tid);
  barrier_lds_only();    // sredf-B ready
  if (tid == 0) {
    double t = 0.0;
    #pragma unroll
    for (int i = 0; i < 8; ++i) t += (double)sredf[i];
    partial[bix1] = t;
  }
  // kernel end: implicit full drain of tile-B stores
}

// --- epilogue: loss = vq + commit = 2 * mean((q - x)^2) ---
__global__ void finish_kernel(const double* __restrict__ partial,
                              float* __restrict__ out) {
  int t = threadIdx.x;   // 256 threads, 1024 partials
  double s = partial[t] + partial[t + 256] + partial[t + 512] + partial[t + 768];
  #pragma unroll
  for (int off = 32; off > 0; off >>= 1) s += __shfl_down(s, off);
  __shared__ double sr[4];
  if ((t & 63) == 0) sr[t >> 6] = s;
  __syncthreads();
  if (t == 0)
    out[0] = (float)(2.0 * (sr[0] + sr[1] + sr[2] + sr[3]) / (double)QSIZE);
}

extern "C" void kernel_launch(void* const* d_in, const int* in_sizes, int n_in,
                              void* d_out, int out_size, void* d_ws, size_t ws_size,
                              hipStream_t stream) {
  const float* x = (const float*)d_in[0];   // [32,64,64,64] f32 NCHW
  const float* w = (const float*)d_in[1];   // [512,64] f32
  float* out = (float*)d_out;
  float* out_q = out + 1;
  float* out_enc = out_q + QSIZE;
  float* out_idx = out_enc + (size_t)NPIX * KC;

  // d_ws layout: partial[1024] @0 (8 KB) | w2g[512] @8192 | wswz[4096] @16384
  double* partial = (double*)d_ws;
  float* w2g = (float*)((char*)d_ws + 8192);
  uint4* wswz = (uint4*)((char*)d_ws + 16384);

  prep<<<4, 1024, 0, stream>>>(w, w2g, wswz);
  vq_fused<<<NBLK, NTH, 0, stream>>>(x, w, w2g, wswz, out_q, out_enc, out_idx, partial);
  finish_kernel<<<1, 256, 0, stream>>>(partial, out);
}